// Round 2
// baseline (1898.243 us; speedup 1.0000x reference)
//
#include <hip/hip_runtime.h>
#include <cmath>

// Causal MHSA, fp32 baseline (no fp32 MFMA on CDNA4 -> vector ALU).
// Stages: QKV NT-GEMM -> RoPE -> flash attention (64x64 tiles, online softmax)
//         -> output NT-GEMM.
// Workspace: Qb/Kb/Vb [64][2048][64] f32 (32MB each) + Ao [4][2048][1024] (32MB).

#define S_LEN 2048
#define NHEAD 16
#define DHEAD 64

// ---------------------------------------------------------------------------
// NT GEMM: C[m,n] = sum_k X[m,k] * W[n,k];  X:[M,1024], W rows: [*,1024]
// Tile 128x128x16, 256 threads, 8x8 micro-tile split as 4+4 (rows tr*4, tr*4+64)
// QKV=1: N spans wq|wk|wv (each 1024 rows); epilogue scatters to [b,h,s,dh].
// QKV=0: plain C[m,n] store (output projection).
// ---------------------------------------------------------------------------
template <int QKV>
__global__ __launch_bounds__(256, 2) void gemm_nt(
    const float* __restrict__ Xin,
    const float* __restrict__ Wq,
    const float* __restrict__ Wk,
    const float* __restrict__ Wv,
    float* __restrict__ O0,
    float* __restrict__ O1,
    float* __restrict__ O2)
{
    __shared__ __align__(16) float As[16][132];  // [k][m], pad->2-way only (free)
    __shared__ __align__(16) float Bs[16][132];  // [k][n]

    const int t  = threadIdx.x;
    const int bm = blockIdx.x * 128;

    int bn;
    const float* Wp;
    float* Ob;
    if constexpr (QKV) {
        const int bng   = blockIdx.y * 128;         // 0..2944
        const int which = bng >> 10;                // 0=q,1=k,2=v (128 | 1024)
        bn = bng & 1023;
        Wp = (which == 0) ? Wq : (which == 1) ? Wk : Wv;
        Ob = (which == 0) ? O0 : (which == 1) ? O1 : O2;
    } else {
        bn = blockIdx.y * 128;
        Wp = Wq;
        Ob = O0;
    }

    const int tr = t >> 4;          // 0..15
    const int tc = t & 15;          // 0..15
    const int lr = t >> 2;          // 0..63  (load row)
    const int lc = (t & 3) * 4;     // 0,4,8,12 (load k-col)

    float acc[8][8] = {};

    const float* xptr = Xin + (size_t)(bm + lr) * 1024 + lc;
    const float* wptr = Wp  + (size_t)(bn + lr) * 1024 + lc;

    for (int k0 = 0; k0 < 1024; k0 += 16) {
        const float4 xa = *(const float4*)(xptr + k0);
        const float4 xb = *(const float4*)(xptr + k0 + (size_t)64 * 1024);
        const float4 wa = *(const float4*)(wptr + k0);
        const float4 wb = *(const float4*)(wptr + k0 + (size_t)64 * 1024);
        __syncthreads();           // previous iter's LDS reads done
        As[lc + 0][lr]      = xa.x; As[lc + 1][lr]      = xa.y;
        As[lc + 2][lr]      = xa.z; As[lc + 3][lr]      = xa.w;
        As[lc + 0][lr + 64] = xb.x; As[lc + 1][lr + 64] = xb.y;
        As[lc + 2][lr + 64] = xb.z; As[lc + 3][lr + 64] = xb.w;
        Bs[lc + 0][lr]      = wa.x; Bs[lc + 1][lr]      = wa.y;
        Bs[lc + 2][lr]      = wa.z; Bs[lc + 3][lr]      = wa.w;
        Bs[lc + 0][lr + 64] = wb.x; Bs[lc + 1][lr + 64] = wb.y;
        Bs[lc + 2][lr + 64] = wb.z; Bs[lc + 3][lr + 64] = wb.w;
        __syncthreads();
        #pragma unroll
        for (int k = 0; k < 16; ++k) {
            const float4 a0 = *(const float4*)&As[k][tr * 4];
            const float4 a1 = *(const float4*)&As[k][tr * 4 + 64];
            const float4 b0 = *(const float4*)&Bs[k][tc * 4];
            const float4 b1 = *(const float4*)&Bs[k][tc * 4 + 64];
            const float av[8] = {a0.x, a0.y, a0.z, a0.w, a1.x, a1.y, a1.z, a1.w};
            const float bv[8] = {b0.x, b0.y, b0.z, b0.w, b1.x, b1.y, b1.z, b1.w};
            #pragma unroll
            for (int i = 0; i < 8; ++i)
                #pragma unroll
                for (int j = 0; j < 8; ++j)
                    acc[i][j] = fmaf(av[i], bv[j], acc[i][j]);
        }
    }

    #pragma unroll
    for (int i = 0; i < 8; ++i) {
        const int m = bm + tr * 4 + (i & 3) + (i >> 2) * 64;
        #pragma unroll
        for (int jj = 0; jj < 2; ++jj) {
            const int n = bn + tc * 4 + jj * 64;
            const float4 v = make_float4(acc[i][jj * 4 + 0], acc[i][jj * 4 + 1],
                                         acc[i][jj * 4 + 2], acc[i][jj * 4 + 3]);
            if constexpr (QKV) {
                const int bb = m >> 11, s = m & 2047;    // m = b*2048+s
                const int h  = n >> 6,  dh = n & 63;
                *(float4*)&Ob[(((size_t)(bb * NHEAD + h) * S_LEN + s)) * DHEAD + dh] = v;
            } else {
                *(float4*)&Ob[(size_t)m * 1024 + n] = v;
            }
        }
    }
}

// ---------------------------------------------------------------------------
// RoPE in-place on Q,K ([bh][s][64] layout, interleaved pairs 2i,2i+1).
// ---------------------------------------------------------------------------
__global__ void rope_kernel(float* __restrict__ Qb, float* __restrict__ Kb)
{
    const int idx  = blockIdx.x * 256 + threadIdx.x;  // 64*2048*32 pairs
    const int i    = idx & 31;
    const int srow = (idx >> 5) & 2047;

    const float inv = powf(10000.0f, -(float)i * (1.0f / 32.0f));
    const float ang = (float)srow * inv;
    float sn, cs;
    sincosf(ang, &sn, &cs);

    const size_t off = (size_t)idx * 2;  // == ((bh*2048+s)*64 + 2i)
    const float2 q = *(const float2*)&Qb[off];
    const float2 k = *(const float2*)&Kb[off];
    *(float2*)&Qb[off] = make_float2(q.x * cs - q.y * sn, q.x * sn + q.y * cs);
    *(float2*)&Kb[off] = make_float2(k.x * cs - k.y * sn, k.x * sn + k.y * cs);
}

// ---------------------------------------------------------------------------
// Flash attention, causal. Block = (qt, bh): 64 q-rows x all keys <= diag.
// 256 threads; S-tile 64x64 via outer product from transposed LDS tiles;
// online softmax (row state replicated over the 16 tc-lanes, shfl_xor reduce);
// PV via P staged transposed in LDS. Output written as [b,s,h,dh] = [B,S,D].
// ---------------------------------------------------------------------------
__global__ __launch_bounds__(256, 2) void attn_kernel(
    const float* __restrict__ Qb, const float* __restrict__ Kb,
    const float* __restrict__ Vb, float* __restrict__ Ao)
{
    __shared__ __align__(16) float Qt[64][68];  // [d][q]
    __shared__ __align__(16) float Kt[64][68];  // [d][c]
    __shared__ __align__(16) float Vs[64][68];  // [c][d]
    __shared__ __align__(16) float Pt[64][68];  // [c][q]

    const int t  = threadIdx.x;
    const int qt = blockIdx.x;    // q tile 0..31
    const int bh = blockIdx.y;    // 0..63
    const int r0 = qt * 64;
    const int tr = t >> 4, tc = t & 15;
    const int lr = t >> 2, lgrp = t & 3;

    const size_t base = (size_t)bh * S_LEN * DHEAD;

    #pragma unroll
    for (int i = 0; i < 4; ++i) {
        const int d = (lgrp + i * 4) * 4;
        const float4 g = *(const float4*)&Qb[base + (size_t)(r0 + lr) * DHEAD + d];
        Qt[d + 0][lr] = g.x; Qt[d + 1][lr] = g.y;
        Qt[d + 2][lr] = g.z; Qt[d + 3][lr] = g.w;
    }

    float m_i[4], l_i[4], o[4][4];
    #pragma unroll
    for (int i = 0; i < 4; ++i) {
        m_i[i] = -INFINITY; l_i[i] = 0.f;
        #pragma unroll
        for (int j = 0; j < 4; ++j) o[i][j] = 0.f;
    }

    for (int kt = 0; kt <= qt; ++kt) {
        const int c0 = kt * 64;
        float4 kg[4], vg[4];
        #pragma unroll
        for (int i = 0; i < 4; ++i) {
            const int d = (lgrp + i * 4) * 4;
            kg[i] = *(const float4*)&Kb[base + (size_t)(c0 + lr) * DHEAD + d];
            vg[i] = *(const float4*)&Vb[base + (size_t)(c0 + lr) * DHEAD + d];
        }
        __syncthreads();   // previous tile's PV reads of Kt/Vs/Pt done
        #pragma unroll
        for (int i = 0; i < 4; ++i) {
            const int d = (lgrp + i * 4) * 4;
            Kt[d + 0][lr] = kg[i].x; Kt[d + 1][lr] = kg[i].y;
            Kt[d + 2][lr] = kg[i].z; Kt[d + 3][lr] = kg[i].w;
            *(float4*)&Vs[lr][d] = vg[i];
        }
        __syncthreads();

        float sv[4][4] = {};
        #pragma unroll 4
        for (int d = 0; d < 64; ++d) {
            const float4 qa = *(const float4*)&Qt[d][tr * 4];
            const float4 kk = *(const float4*)&Kt[d][tc * 4];
            const float qv[4] = {qa.x, qa.y, qa.z, qa.w};
            const float kv[4] = {kk.x, kk.y, kk.z, kk.w};
            #pragma unroll
            for (int i = 0; i < 4; ++i)
                #pragma unroll
                for (int j = 0; j < 4; ++j)
                    sv[i][j] = fmaf(qv[i], kv[j], sv[i][j]);
        }
        #pragma unroll
        for (int i = 0; i < 4; ++i)
            #pragma unroll
            for (int j = 0; j < 4; ++j)
                sv[i][j] *= 0.125f;  // 1/sqrt(64)
        if (kt == qt) {
            #pragma unroll
            for (int i = 0; i < 4; ++i)
                #pragma unroll
                for (int j = 0; j < 4; ++j)
                    if (c0 + tc * 4 + j > r0 + tr * 4 + i) sv[i][j] = -INFINITY;
        }

        float al[4];
        #pragma unroll
        for (int i = 0; i < 4; ++i) {
            float v0 = fmaxf(fmaxf(sv[i][0], sv[i][1]), fmaxf(sv[i][2], sv[i][3]));
            v0 = fmaxf(v0, __shfl_xor(v0, 1));
            v0 = fmaxf(v0, __shfl_xor(v0, 2));
            v0 = fmaxf(v0, __shfl_xor(v0, 4));
            v0 = fmaxf(v0, __shfl_xor(v0, 8));
            const float mn = fmaxf(m_i[i], v0);     // row has >=1 unmasked entry
            al[i] = __expf(m_i[i] - mn);
            m_i[i] = mn;
        }
        #pragma unroll
        for (int i = 0; i < 4; ++i) {
            #pragma unroll
            for (int j = 0; j < 4; ++j) sv[i][j] = __expf(sv[i][j] - m_i[i]);
            float r = sv[i][0] + sv[i][1] + sv[i][2] + sv[i][3];
            r += __shfl_xor(r, 1);
            r += __shfl_xor(r, 2);
            r += __shfl_xor(r, 4);
            r += __shfl_xor(r, 8);
            l_i[i] = l_i[i] * al[i] + r;
            #pragma unroll
            for (int j = 0; j < 4; ++j) o[i][j] *= al[i];
        }

        #pragma unroll
        for (int i = 0; i < 4; ++i)
            #pragma unroll
            for (int j = 0; j < 4; ++j)
                Pt[tc * 4 + j][tr * 4 + i] = sv[i][j];
        __syncthreads();

        #pragma unroll 4
        for (int c = 0; c < 64; ++c) {
            const float4 pa = *(const float4*)&Pt[c][tr * 4];
            const float4 vv = *(const float4*)&Vs[c][tc * 4];
            const float pv[4] = {pa.x, pa.y, pa.z, pa.w};
            const float vb[4] = {vv.x, vv.y, vv.z, vv.w};
            #pragma unroll
            for (int i = 0; i < 4; ++i)
                #pragma unroll
                for (int j = 0; j < 4; ++j)
                    o[i][j] = fmaf(pv[i], vb[j], o[i][j]);
        }
    }

    const int bb = bh >> 4, h = bh & 15;
    #pragma unroll
    for (int i = 0; i < 4; ++i) {
        const float inv = 1.0f / l_i[i];
        const int s = r0 + tr * 4 + i;
        const float4 v = make_float4(o[i][0] * inv, o[i][1] * inv,
                                     o[i][2] * inv, o[i][3] * inv);
        *(float4*)&Ao[((size_t)(bb * S_LEN + s)) * 1024 + h * 64 + tc * 4] = v;
    }
}

// ---------------------------------------------------------------------------
extern "C" void kernel_launch(void* const* d_in, const int* in_sizes, int n_in,
                              void* d_out, int out_size, void* d_ws, size_t ws_size,
                              hipStream_t stream)
{
    const float* x  = (const float*)d_in[0];
    const float* wq = (const float*)d_in[1];
    const float* wk = (const float*)d_in[2];
    const float* wv = (const float*)d_in[3];
    const float* wo = (const float*)d_in[4];
    float* out = (float*)d_out;

    float* ws = (float*)d_ws;
    const size_t NE = (size_t)64 * S_LEN * DHEAD;  // 8,388,608 elems per tensor
    float* Qb = ws;
    float* Kb = ws + NE;
    float* Vb = ws + 2 * NE;
    float* Ao = ws + 3 * NE;   // [B,S,D]

    // QKV projection: M=8192, N=3072
    gemm_nt<1><<<dim3(64, 24), 256, 0, stream>>>(x, wq, wk, wv, Qb, Kb, Vb);
    // RoPE on Q,K
    rope_kernel<<<dim3(16384), 256, 0, stream>>>(Qb, Kb);
    // causal flash attention
    attn_kernel<<<dim3(32, 64), 256, 0, stream>>>(Qb, Kb, Vb, Ao);
    // output projection: M=8192, N=1024
    gemm_nt<0><<<dim3(64, 8), 256, 0, stream>>>(Ao, wo, nullptr, nullptr,
                                                out, nullptr, nullptr);
}

// Round 4
// 418.140 us; speedup vs baseline: 4.5397x; 4.5397x over previous
//
#include <hip/hip_runtime.h>
#include <cmath>

// Causal MHSA on MI355X, bf16-MFMA version.
// cast(x,W) -> QKV NT-GEMM (mfma bf16, m97 structure) -> RoPE(bf16) ->
// MFMA flash attention (swizzled LDS K/V, P via LDS) -> out NT-GEMM (f32 out).

#define S_LEN 2048
#define NHEAD 16
#define DHEAD 64

typedef short bf16x8 __attribute__((ext_vector_type(8)));
typedef float f32x4  __attribute__((ext_vector_type(4)));
typedef unsigned short u16x4 __attribute__((ext_vector_type(4)));

__device__ __forceinline__ float bf2f(unsigned short u) {
    unsigned x = ((unsigned)u) << 16;
    return __builtin_bit_cast(float, x);
}
__device__ __forceinline__ unsigned short f2bf(float f) {   // RNE
    unsigned u = __builtin_bit_cast(unsigned, f);
    unsigned r = u + 0x7fff + ((u >> 16) & 1);
    return (unsigned short)(r >> 16);
}
__device__ __forceinline__ void gl16(const void* g, void* l) {
    __builtin_amdgcn_global_load_lds(
        (const __attribute__((address_space(1))) unsigned int*)g,
        (__attribute__((address_space(3))) unsigned int*)l, 16, 0, 0);
}

// ---------------------------------------------------------------------------
// f32 -> bf16 cast, 8 elems/thread
// ---------------------------------------------------------------------------
__global__ void cast_f32_bf16(const float* __restrict__ in,
                              unsigned short* __restrict__ out, int n)
{
    const int i = (blockIdx.x * 256 + threadIdx.x) * 8;
    if (i >= n) return;
    const float4 a = *(const float4*)(in + i);
    const float4 b = *(const float4*)(in + i + 4);
    bf16x8 o;
    o[0] = (short)f2bf(a.x); o[1] = (short)f2bf(a.y);
    o[2] = (short)f2bf(a.z); o[3] = (short)f2bf(a.w);
    o[4] = (short)f2bf(b.x); o[5] = (short)f2bf(b.y);
    o[6] = (short)f2bf(b.z); o[7] = (short)f2bf(b.w);
    *(bf16x8*)(out + i) = o;
}

// ---------------------------------------------------------------------------
// NT GEMM, bf16 MFMA (m97 structure): C = A[M,1024] * B[N,1024]^T
// 128x128 tile, BK=32, 256 thr (4 waves 2x2), acc 4x4 frags of 16x16.
// MODE 0: QKV — scatter bf16 to Qb/Kb [bh][s][64] and Vt [bh][dh][2048].
// MODE 1: OUT — f32 store to Co[M][1024].
// ---------------------------------------------------------------------------
template <int MODE>
__global__ __launch_bounds__(256, 2) void gemm_bt(
    const unsigned short* __restrict__ A,
    const unsigned short* __restrict__ Bw,
    unsigned short* __restrict__ Qb,
    unsigned short* __restrict__ Kb,
    unsigned short* __restrict__ Vt,
    float* __restrict__ Co)
{
    __shared__ __align__(16) unsigned short As[128 * 32];
    __shared__ __align__(16) unsigned short Bs[128 * 32];

    const int t    = threadIdx.x;
    const int bm   = blockIdx.x * 128;
    const int bn   = blockIdx.y * 128;
    const int lane = t & 63, wv = t >> 6;
    const int wr   = wv >> 1, wc = wv & 1;
    const int ln   = lane & 15, ko = lane >> 4;

    f32x4 acc[4][4];
    #pragma unroll
    for (int i = 0; i < 4; ++i)
        #pragma unroll
        for (int j = 0; j < 4; ++j)
            acc[i][j] = f32x4{0.f, 0.f, 0.f, 0.f};

    const int ar  = t >> 2;          // 0..63
    const int asg = t & 3;           // 16B segment of a 64B row-chunk
    const unsigned short* aptr = A  + (size_t)(bm + ar) * 1024 + asg * 8;
    const unsigned short* bptr = Bw + (size_t)(bn + ar) * 1024 + asg * 8;

    for (int k0 = 0; k0 < 1024; k0 += 32) {
        __syncthreads();
        gl16(aptr + k0,               (char*)As + t * 16);
        gl16(aptr + k0 + 64 * 1024,   (char*)As + (t + 256) * 16);
        gl16(bptr + k0,               (char*)Bs + t * 16);
        gl16(bptr + k0 + 64 * 1024,   (char*)Bs + (t + 256) * 16);
        __syncthreads();

        bf16x8 af[4], bfr[4];
        #pragma unroll
        for (int i = 0; i < 4; ++i)
            af[i] = *(const bf16x8*)((const char*)As + (wr * 64 + i * 16 + ln) * 64 + ko * 16);
        #pragma unroll
        for (int j = 0; j < 4; ++j)
            bfr[j] = *(const bf16x8*)((const char*)Bs + (wc * 64 + j * 16 + ln) * 64 + ko * 16);
        #pragma unroll
        for (int i = 0; i < 4; ++i)
            #pragma unroll
            for (int j = 0; j < 4; ++j)
                acc[i][j] = __builtin_amdgcn_mfma_f32_16x16x32_bf16(af[i], bfr[j], acc[i][j], 0, 0, 0);
    }

    #pragma unroll
    for (int i = 0; i < 4; ++i) {
        const int mb = bm + wr * 64 + i * 16 + ko * 4;   // 4 consecutive rows mb..mb+3
        #pragma unroll
        for (int j = 0; j < 4; ++j) {
            const int n = bn + wc * 64 + j * 16 + ln;
            if constexpr (MODE == 0) {
                const int which = n >> 10, nh = n & 1023;
                const int h = nh >> 6, dh = nh & 63;
                const int bb = mb >> 11, s = mb & 2047;
                const int bh = bb * NHEAD + h;
                if (which == 2) {
                    u16x4 pk;
                    #pragma unroll
                    for (int r = 0; r < 4; ++r) pk[r] = f2bf(acc[i][j][r]);
                    *(u16x4*)&Vt[((size_t)bh * 64 + dh) * 2048 + s] = pk;
                } else {
                    unsigned short* dst = which ? Kb : Qb;
                    #pragma unroll
                    for (int r = 0; r < 4; ++r)
                        dst[((size_t)bh * 2048 + (s + r)) * 64 + dh] = f2bf(acc[i][j][r]);
                }
            } else {
                #pragma unroll
                for (int r = 0; r < 4; ++r)
                    Co[(size_t)(mb + r) * 1024 + n] = acc[i][j][r];
            }
        }
    }
}

// ---------------------------------------------------------------------------
// RoPE in-place on bf16 Q,K ([bh][s][64], interleaved pairs)
// ---------------------------------------------------------------------------
__global__ void rope_kernel(unsigned int* __restrict__ Qb, unsigned int* __restrict__ Kb)
{
    const int idx  = blockIdx.x * 256 + threadIdx.x;  // 64*2048*32 pairs
    const int i    = idx & 31;
    const int srow = (idx >> 5) & 2047;

    const float inv = powf(10000.0f, -(float)i * (1.0f / 32.0f));
    const float ang = (float)srow * inv;
    float sn, cs;
    sincosf(ang, &sn, &cs);

    const unsigned q = Qb[idx];
    const unsigned k = Kb[idx];
    const float qx = bf2f((unsigned short)(q & 0xffff)), qy = bf2f((unsigned short)(q >> 16));
    const float kx = bf2f((unsigned short)(k & 0xffff)), ky = bf2f((unsigned short)(k >> 16));
    const unsigned qo = (unsigned)f2bf(qx * cs - qy * sn) | ((unsigned)f2bf(qx * sn + qy * cs) << 16);
    const unsigned ko = (unsigned)f2bf(kx * cs - ky * sn) | ((unsigned)f2bf(kx * sn + ky * cs) << 16);
    Qb[idx] = qo;
    Kb[idx] = ko;
}

// ---------------------------------------------------------------------------
// MFMA flash attention, causal. Block=(qt,bh), 256 thr = 4 waves x 16 q-rows.
// K_lds [key][dh] and V_lds [dh][key] staged via global_load_lds with
// pre-swizzled source (XOR of 16B-span by row&7) + swizzled ds_read (rule 21).
// Softmax in D-frags (16-lane shfl groups); P via per-wave swizzled LDS.
// ---------------------------------------------------------------------------
__global__ __launch_bounds__(256, 2) void attn_mfma(
    const unsigned short* __restrict__ Qb,
    const unsigned short* __restrict__ Kb,
    const unsigned short* __restrict__ Vt,
    unsigned short* __restrict__ Aot)
{
    __shared__ __align__(16) unsigned short Ksh[64 * 64];
    __shared__ __align__(16) unsigned short Vsh[64 * 64];
    __shared__ __align__(16) unsigned short Psh[4 * 16 * 64];

    const int t    = threadIdx.x;
    const int lane = t & 63, w = t >> 6;
    const int ln   = lane & 15, koct = lane >> 4;
    const int qt   = 31 - blockIdx.x;          // heavy blocks first
    const int bh   = blockIdx.y;
    const int r0   = qt * 64;
    const size_t kvbase = (size_t)bh * S_LEN * DHEAD;
    const size_t vtbase = (size_t)bh * DHEAD * S_LEN;

    // Q fragments, pre-scaled by 1/8 (exact in bf16)
    bf16x8 qf[2];
    #pragma unroll
    for (int s = 0; s < 2; ++s) {
        bf16x8 v = *(const bf16x8*)(Qb + kvbase + (size_t)(r0 + w * 16 + ln) * 64 + s * 32 + koct * 8);
        #pragma unroll
        for (int j = 0; j < 8; ++j)
            v[j] = (short)f2bf(bf2f((unsigned short)v[j]) * 0.125f);
        qf[s] = v;
    }

    f32x4 ao[4];
    float m_i[4], l_i[4];
    #pragma unroll
    for (int r = 0; r < 4; ++r) { m_i[r] = -INFINITY; l_i[r] = 0.f; }
    #pragma unroll
    for (int nf = 0; nf < 4; ++nf) ao[nf] = f32x4{0.f, 0.f, 0.f, 0.f};

    const int kr  = t >> 3;        // staging row (first instr), +32 second
    const int sg  = t & 7;         // 16B segment within 128B row

    for (int kt = 0; kt <= qt; ++kt) {
        const int c0 = kt * 64;
        __syncthreads();   // all waves done reading K/V of previous tile
        {
            const int kr2 = kr + 32;
            gl16(Kb + kvbase + (size_t)(c0 + kr)  * 64 + (sg ^ (kr  & 7)) * 8, (char*)Ksh + t * 16);
            gl16(Kb + kvbase + (size_t)(c0 + kr2) * 64 + (sg ^ (kr2 & 7)) * 8, (char*)Ksh + (t + 256) * 16);
            gl16(Vt + vtbase + (size_t)kr  * S_LEN + c0 + (sg ^ (kr  & 7)) * 8, (char*)Vsh + t * 16);
            gl16(Vt + vtbase + (size_t)kr2 * S_LEN + c0 + (sg ^ (kr2 & 7)) * 8, (char*)Vsh + (t + 256) * 16);
        }
        __syncthreads();   // barrier drains vmcnt -> tiles visible

        // ---- QK^T: S[16q][64key], acc over dh (2 k-steps) ----
        f32x4 sv[4];
        #pragma unroll
        for (int nf = 0; nf < 4; ++nf) sv[nf] = f32x4{0.f, 0.f, 0.f, 0.f};
        #pragma unroll
        for (int s = 0; s < 2; ++s) {
            #pragma unroll
            for (int nf = 0; nf < 4; ++nf) {
                const int key = nf * 16 + ln;
                const bf16x8 kf = *(const bf16x8*)((const char*)Ksh + key * 128 + (((s * 4 + koct) ^ (key & 7)) * 16));
                sv[nf] = __builtin_amdgcn_mfma_f32_16x16x32_bf16(qf[s], kf, sv[nf], 0, 0, 0);
            }
        }

        if (kt == qt) {   // diagonal tile: causal mask
            #pragma unroll
            for (int nf = 0; nf < 4; ++nf) {
                const int key = c0 + nf * 16 + ln;
                #pragma unroll
                for (int r = 0; r < 4; ++r)
                    if (key > r0 + w * 16 + koct * 4 + r) sv[nf][r] = -INFINITY;
            }
        }

        // ---- online softmax (row q = w*16 + koct*4 + r, reduce over 16 lanes) ----
        float al[4];
        #pragma unroll
        for (int r = 0; r < 4; ++r) {
            float mx = fmaxf(fmaxf(sv[0][r], sv[1][r]), fmaxf(sv[2][r], sv[3][r]));
            mx = fmaxf(mx, __shfl_xor(mx, 1));
            mx = fmaxf(mx, __shfl_xor(mx, 2));
            mx = fmaxf(mx, __shfl_xor(mx, 4));
            mx = fmaxf(mx, __shfl_xor(mx, 8));
            const float mn = fmaxf(m_i[r], mx);
            al[r] = __expf(m_i[r] - mn);
            m_i[r] = mn;
            float sum = 0.f;
            #pragma unroll
            for (int nf = 0; nf < 4; ++nf) {
                const float p = __expf(sv[nf][r] - mn);
                sv[nf][r] = p;
                sum += p;
            }
            sum += __shfl_xor(sum, 1);
            sum += __shfl_xor(sum, 2);
            sum += __shfl_xor(sum, 4);
            sum += __shfl_xor(sum, 8);
            l_i[r] = l_i[r] * al[r] + sum;
        }
        #pragma unroll
        for (int nf = 0; nf < 4; ++nf)
            #pragma unroll
            for (int r = 0; r < 4; ++r)
                ao[nf][r] *= al[r];

        // ---- P -> per-wave LDS (bf16, swizzled rows of 128B) ----
        char* pb = (char*)Psh + w * 2048;
        #pragma unroll
        for (int nf = 0; nf < 4; ++nf) {
            const int key = nf * 16 + ln;
            #pragma unroll
            for (int r = 0; r < 4; ++r) {
                const int q = koct * 4 + r;
                *(unsigned short*)(pb + q * 128 + ((key * 2) ^ ((q & 7) << 4))) = f2bf(sv[nf][r]);
            }
        }
        // no barrier: P is wave-private; lgkmcnt ordering handled by compiler

        // ---- PV: O[16q][64dh] += P[16,64] * V[64,64] ----
        #pragma unroll
        for (int s2 = 0; s2 < 2; ++s2) {
            const bf16x8 pa = *(const bf16x8*)(pb + ln * 128 + (((s2 * 4 + koct) ^ (ln & 7)) * 16));
            #pragma unroll
            for (int nf = 0; nf < 4; ++nf) {
                const int dh = nf * 16 + ln;
                const bf16x8 vf = *(const bf16x8*)((const char*)Vsh + dh * 128 + (((s2 * 4 + koct) ^ (dh & 7)) * 16));
                ao[nf] = __builtin_amdgcn_mfma_f32_16x16x32_bf16(pa, vf, ao[nf], 0, 0, 0);
            }
        }
    }

    // ---- epilogue: Aot [b][s][h*64+dh] bf16 ----
    const int b = bh >> 4, h = bh & 15;
    #pragma unroll
    for (int r = 0; r < 4; ++r) {
        const float inv = 1.0f / l_i[r];
        const int s = r0 + w * 16 + koct * 4 + r;
        #pragma unroll
        for (int nf = 0; nf < 4; ++nf)
            Aot[(size_t)(b * S_LEN + s) * 1024 + h * 64 + nf * 16 + ln] = f2bf(ao[nf][r] * inv);
    }
}

// ---------------------------------------------------------------------------
extern "C" void kernel_launch(void* const* d_in, const int* in_sizes, int n_in,
                              void* d_out, int out_size, void* d_ws, size_t ws_size,
                              hipStream_t stream)
{
    const float* x  = (const float*)d_in[0];
    const float* wq = (const float*)d_in[1];
    const float* wk = (const float*)d_in[2];
    const float* wv = (const float*)d_in[3];
    const float* wo = (const float*)d_in[4];
    float* out = (float*)d_out;

    char* p = (char*)d_ws;
    unsigned short* Xb  = (unsigned short*)p;                          // 16 MB
    unsigned short* Wb  = (unsigned short*)(p + ((size_t)16 << 20));   // 6 MB [3072][1024]
    unsigned short* Wob = (unsigned short*)(p + ((size_t)22 << 20));   // 2 MB
    unsigned short* Qb  = (unsigned short*)(p + ((size_t)24 << 20));   // 16 MB [bh][s][64]
    unsigned short* Kb  = (unsigned short*)(p + ((size_t)40 << 20));   // 16 MB
    unsigned short* Vt  = (unsigned short*)(p + ((size_t)56 << 20));   // 16 MB [bh][dh][s]
    unsigned short* Aot = (unsigned short*)(p + ((size_t)72 << 20));   // 16 MB [b][s][1024]

    const int NX = 8192 * 1024, NW = 1024 * 1024;
    cast_f32_bf16<<<NX / 2048, 256, 0, stream>>>(x,  Xb, NX);
    cast_f32_bf16<<<NW / 2048, 256, 0, stream>>>(wq, Wb, NW);
    cast_f32_bf16<<<NW / 2048, 256, 0, stream>>>(wk, Wb + NW, NW);
    cast_f32_bf16<<<NW / 2048, 256, 0, stream>>>(wv, Wb + 2 * NW, NW);
    cast_f32_bf16<<<NW / 2048, 256, 0, stream>>>(wo, Wob, NW);

    gemm_bt<0><<<dim3(64, 24), 256, 0, stream>>>(Xb, Wb, Qb, Kb, Vt, nullptr);
    rope_kernel<<<16384, 256, 0, stream>>>((unsigned int*)Qb, (unsigned int*)Kb);
    attn_mfma<<<dim3(32, 64), 256, 0, stream>>>(Qb, Kb, Vt, Aot);
    gemm_bt<1><<<dim3(64, 8), 256, 0, stream>>>(Aot, Wob, nullptr, nullptr, nullptr, out);
}

// Round 5
// 369.099 us; speedup vs baseline: 5.1429x; 1.1329x over previous
//
#include <hip/hip_runtime.h>
#include <cmath>

// Causal MHSA on MI355X, bf16-MFMA version, round 5.
// cast(x) + fused cast(w*) -> QKV NT-GEMM (mfma bf16) -> RoPE(bf16) ->
// paired-tile double-buffered MFMA flash attention -> out NT-GEMM (f32 out).

#define S_LEN 2048
#define NHEAD 16
#define DHEAD 64

typedef short bf16x8 __attribute__((ext_vector_type(8)));
typedef float f32x4  __attribute__((ext_vector_type(4)));
typedef unsigned short u16x4 __attribute__((ext_vector_type(4)));

__device__ __forceinline__ float bf2f(unsigned short u) {
    unsigned x = ((unsigned)u) << 16;
    return __builtin_bit_cast(float, x);
}
__device__ __forceinline__ unsigned short f2bf(float f) {   // RNE
    unsigned u = __builtin_bit_cast(unsigned, f);
    unsigned r = u + 0x7fff + ((u >> 16) & 1);
    return (unsigned short)(r >> 16);
}
__device__ __forceinline__ void gl16(const void* g, void* l) {
    __builtin_amdgcn_global_load_lds(
        (const __attribute__((address_space(1))) unsigned int*)g,
        (__attribute__((address_space(3))) unsigned int*)l, 16, 0, 0);
}

// ---------------------------------------------------------------------------
// f32 -> bf16 cast, 8 elems/thread (for x)
// ---------------------------------------------------------------------------
__global__ void cast_f32_bf16(const float* __restrict__ in,
                              unsigned short* __restrict__ out, int n)
{
    const int i = (blockIdx.x * 256 + threadIdx.x) * 8;
    if (i >= n) return;
    const float4 a = *(const float4*)(in + i);
    const float4 b = *(const float4*)(in + i + 4);
    bf16x8 o;
    o[0] = (short)f2bf(a.x); o[1] = (short)f2bf(a.y);
    o[2] = (short)f2bf(a.z); o[3] = (short)f2bf(a.w);
    o[4] = (short)f2bf(b.x); o[5] = (short)f2bf(b.y);
    o[6] = (short)f2bf(b.z); o[7] = (short)f2bf(b.w);
    *(bf16x8*)(out + i) = o;
}

// Fused cast of wq/wk/wv/wo (1M elems each) in one launch.
__global__ void cast_w4(const float* __restrict__ wq, const float* __restrict__ wk,
                        const float* __restrict__ wv, const float* __restrict__ wo,
                        unsigned short* __restrict__ Wb, unsigned short* __restrict__ Wob)
{
    const int idx = blockIdx.x * 256 + threadIdx.x;     // 524288 total threads
    const int sel = idx >> 17;                          // 0..3 (131072 thr each)
    const int loc = idx & 131071;
    const float* src = (sel == 0) ? wq : (sel == 1) ? wk : (sel == 2) ? wv : wo;
    unsigned short* dst = (sel == 3) ? Wob : Wb + (size_t)sel * 1048576;
    const int i = loc * 8;
    const float4 a = *(const float4*)(src + i);
    const float4 b = *(const float4*)(src + i + 4);
    bf16x8 o;
    o[0] = (short)f2bf(a.x); o[1] = (short)f2bf(a.y);
    o[2] = (short)f2bf(a.z); o[3] = (short)f2bf(a.w);
    o[4] = (short)f2bf(b.x); o[5] = (short)f2bf(b.y);
    o[6] = (short)f2bf(b.z); o[7] = (short)f2bf(b.w);
    *(bf16x8*)(dst + i) = o;
}

// ---------------------------------------------------------------------------
// NT GEMM, bf16 MFMA (m97 structure): C = A[M,1024] * B[N,1024]^T
// 128x128 tile, BK=32, 256 thr (4 waves 2x2), acc 4x4 frags of 16x16.
// MODE 0: QKV — scatter bf16 to Qb/Kb [bh][s][64] and Vt [bh][dh][2048].
// MODE 1: OUT — f32 store to Co[M][1024].
// ---------------------------------------------------------------------------
template <int MODE>
__global__ __launch_bounds__(256, 2) void gemm_bt(
    const unsigned short* __restrict__ A,
    const unsigned short* __restrict__ Bw,
    unsigned short* __restrict__ Qb,
    unsigned short* __restrict__ Kb,
    unsigned short* __restrict__ Vt,
    float* __restrict__ Co)
{
    __shared__ __align__(16) unsigned short As[128 * 32];
    __shared__ __align__(16) unsigned short Bs[128 * 32];

    const int t    = threadIdx.x;
    const int bm   = blockIdx.x * 128;
    const int bn   = blockIdx.y * 128;
    const int lane = t & 63, wv = t >> 6;
    const int wr   = wv >> 1, wc = wv & 1;
    const int ln   = lane & 15, ko = lane >> 4;

    f32x4 acc[4][4];
    #pragma unroll
    for (int i = 0; i < 4; ++i)
        #pragma unroll
        for (int j = 0; j < 4; ++j)
            acc[i][j] = f32x4{0.f, 0.f, 0.f, 0.f};

    const int ar  = t >> 2;          // 0..63
    const int asg = t & 3;           // 16B segment of a 64B row-chunk
    const unsigned short* aptr = A  + (size_t)(bm + ar) * 1024 + asg * 8;
    const unsigned short* bptr = Bw + (size_t)(bn + ar) * 1024 + asg * 8;

    for (int k0 = 0; k0 < 1024; k0 += 32) {
        __syncthreads();
        gl16(aptr + k0,               (char*)As + t * 16);
        gl16(aptr + k0 + 64 * 1024,   (char*)As + (t + 256) * 16);
        gl16(bptr + k0,               (char*)Bs + t * 16);
        gl16(bptr + k0 + 64 * 1024,   (char*)Bs + (t + 256) * 16);
        __syncthreads();

        bf16x8 af[4], bfr[4];
        #pragma unroll
        for (int i = 0; i < 4; ++i)
            af[i] = *(const bf16x8*)((const char*)As + (wr * 64 + i * 16 + ln) * 64 + ko * 16);
        #pragma unroll
        for (int j = 0; j < 4; ++j)
            bfr[j] = *(const bf16x8*)((const char*)Bs + (wc * 64 + j * 16 + ln) * 64 + ko * 16);
        #pragma unroll
        for (int i = 0; i < 4; ++i)
            #pragma unroll
            for (int j = 0; j < 4; ++j)
                acc[i][j] = __builtin_amdgcn_mfma_f32_16x16x32_bf16(af[i], bfr[j], acc[i][j], 0, 0, 0);
    }

    #pragma unroll
    for (int i = 0; i < 4; ++i) {
        const int mb = bm + wr * 64 + i * 16 + ko * 4;   // 4 consecutive rows mb..mb+3
        #pragma unroll
        for (int j = 0; j < 4; ++j) {
            const int n = bn + wc * 64 + j * 16 + ln;
            if constexpr (MODE == 0) {
                const int which = n >> 10, nh = n & 1023;
                const int h = nh >> 6, dh = nh & 63;
                const int bb = mb >> 11, s = mb & 2047;
                const int bh = bb * NHEAD + h;
                if (which == 2) {
                    u16x4 pk;
                    #pragma unroll
                    for (int r = 0; r < 4; ++r) pk[r] = f2bf(acc[i][j][r]);
                    *(u16x4*)&Vt[((size_t)bh * 64 + dh) * 2048 + s] = pk;
                } else {
                    unsigned short* dst = which ? Kb : Qb;
                    #pragma unroll
                    for (int r = 0; r < 4; ++r)
                        dst[((size_t)bh * 2048 + (s + r)) * 64 + dh] = f2bf(acc[i][j][r]);
                }
            } else {
                #pragma unroll
                for (int r = 0; r < 4; ++r)
                    Co[(size_t)(mb + r) * 1024 + n] = acc[i][j][r];
            }
        }
    }
}

// ---------------------------------------------------------------------------
// RoPE in-place on bf16 Q,K ([bh][s][64], interleaved pairs)
// ---------------------------------------------------------------------------
__global__ void rope_kernel(unsigned int* __restrict__ Qb, unsigned int* __restrict__ Kb)
{
    const int idx  = blockIdx.x * 256 + threadIdx.x;  // 64*2048*32 pairs
    const int i    = idx & 31;
    const int srow = (idx >> 5) & 2047;

    const float inv = powf(10000.0f, -(float)i * (1.0f / 32.0f));
    const float ang = (float)srow * inv;
    float sn, cs;
    sincosf(ang, &sn, &cs);

    const unsigned q = Qb[idx];
    const unsigned k = Kb[idx];
    const float qx = bf2f((unsigned short)(q & 0xffff)), qy = bf2f((unsigned short)(q >> 16));
    const float kx = bf2f((unsigned short)(k & 0xffff)), ky = bf2f((unsigned short)(k >> 16));
    const unsigned qo = (unsigned)f2bf(qx * cs - qy * sn) | ((unsigned)f2bf(qx * sn + qy * cs) << 16);
    const unsigned ko = (unsigned)f2bf(kx * cs - ky * sn) | ((unsigned)f2bf(kx * sn + ky * cs) << 16);
    Qb[idx] = qo;
    Kb[idx] = ko;
}

// ---------------------------------------------------------------------------
// One 64-key tile for one 64-q tile: QK^T -> online softmax -> P(LDS) -> PV.
// mrow >= 64: no causal mask; else mask keys ki > mrow + r (diagonal tile).
// ---------------------------------------------------------------------------
__device__ __forceinline__ void process_tile(
    const char* __restrict__ Ks, const char* __restrict__ Vs, char* pb,
    const bf16x8 qf[2], f32x4 ao[4], float m_i[4], float l_i[4],
    int ln, int koct, int mrow)
{
    // ---- QK^T: S[16q][64key] ----
    f32x4 sv[4];
    #pragma unroll
    for (int nf = 0; nf < 4; ++nf) sv[nf] = f32x4{0.f, 0.f, 0.f, 0.f};
    #pragma unroll
    for (int s = 0; s < 2; ++s) {
        #pragma unroll
        for (int nf = 0; nf < 4; ++nf) {
            const int key = nf * 16 + ln;
            const bf16x8 kf = *(const bf16x8*)(Ks + key * 128 + (((s * 4 + koct) ^ (key & 7)) * 16));
            sv[nf] = __builtin_amdgcn_mfma_f32_16x16x32_bf16(qf[s], kf, sv[nf], 0, 0, 0);
        }
    }

    if (mrow < 64) {   // diagonal tile: causal mask
        #pragma unroll
        for (int nf = 0; nf < 4; ++nf) {
            const int key = nf * 16 + ln;
            #pragma unroll
            for (int r = 0; r < 4; ++r)
                if (key > mrow + r) sv[nf][r] = -INFINITY;
        }
    }

    // ---- online softmax (row q = koct*4 + r within wave, 16-lane reduce) ----
    float al[4];
    #pragma unroll
    for (int r = 0; r < 4; ++r) {
        float mx = fmaxf(fmaxf(sv[0][r], sv[1][r]), fmaxf(sv[2][r], sv[3][r]));
        mx = fmaxf(mx, __shfl_xor(mx, 1));
        mx = fmaxf(mx, __shfl_xor(mx, 2));
        mx = fmaxf(mx, __shfl_xor(mx, 4));
        mx = fmaxf(mx, __shfl_xor(mx, 8));
        const float mn = fmaxf(m_i[r], mx);
        al[r] = __expf(m_i[r] - mn);
        m_i[r] = mn;
        float sum = 0.f;
        #pragma unroll
        for (int nf = 0; nf < 4; ++nf) {
            const float p = __expf(sv[nf][r] - mn);
            sv[nf][r] = p;
            sum += p;
        }
        sum += __shfl_xor(sum, 1);
        sum += __shfl_xor(sum, 2);
        sum += __shfl_xor(sum, 4);
        sum += __shfl_xor(sum, 8);
        l_i[r] = l_i[r] * al[r] + sum;
    }
    #pragma unroll
    for (int nf = 0; nf < 4; ++nf)
        #pragma unroll
        for (int r = 0; r < 4; ++r)
            ao[nf][r] *= al[r];

    // ---- P -> per-wave LDS (bf16, swizzled rows of 128B) ----
    #pragma unroll
    for (int nf = 0; nf < 4; ++nf) {
        const int key = nf * 16 + ln;
        #pragma unroll
        for (int r = 0; r < 4; ++r) {
            const int q = koct * 4 + r;
            *(unsigned short*)(pb + q * 128 + ((key * 2) ^ ((q & 7) << 4))) = f2bf(sv[nf][r]);
        }
    }
    // wave-private P; same-wave lgkm ordering handled by compiler

    // ---- PV: O[16q][64dh] += P[16,64] * V[64,64] ----
    #pragma unroll
    for (int s2 = 0; s2 < 2; ++s2) {
        const bf16x8 pa = *(const bf16x8*)(pb + ln * 128 + (((s2 * 4 + koct) ^ (ln & 7)) * 16));
        #pragma unroll
        for (int nf = 0; nf < 4; ++nf) {
            const int dh = nf * 16 + ln;
            const bf16x8 vf = *(const bf16x8*)(Vs + dh * 128 + (((s2 * 4 + koct) ^ (dh & 7)) * 16));
            ao[nf] = __builtin_amdgcn_mfma_f32_16x16x32_bf16(pa, vf, ao[nf], 0, 0, 0);
        }
    }
}

// ---------------------------------------------------------------------------
// MFMA flash attention, causal, PAIRED q-tiles (qtA = bx, qtB = 31-bx) so all
// blocks do 33 tiles (perfect balance). K/V double-buffered, staged for the
// NEXT kt before computing current (2-phase pipeline, 1 barrier/tile).
// ---------------------------------------------------------------------------
__global__ __launch_bounds__(256, 3) void attn_mfma(
    const unsigned short* __restrict__ Qb,
    const unsigned short* __restrict__ Kb,
    const unsigned short* __restrict__ Vt,
    unsigned short* __restrict__ Aot)
{
    __shared__ __align__(16) unsigned short Ksh[2][64 * 64];
    __shared__ __align__(16) unsigned short Vsh[2][64 * 64];
    __shared__ __align__(16) unsigned short Psh[4 * 16 * 64];

    const int t    = threadIdx.x;
    const int lane = t & 63, w = t >> 6;
    const int ln   = lane & 15, koct = lane >> 4;
    const int qtA  = blockIdx.x;          // 0..15
    const int qtB  = 31 - qtA;            // 31..16
    const int bh   = blockIdx.y;
    const int rA   = qtA * 64, rB = qtB * 64;
    const size_t kvbase = (size_t)bh * S_LEN * DHEAD;
    const size_t vtbase = (size_t)bh * DHEAD * S_LEN;

    // Q fragments for both tiles, pre-scaled by 1/8 (exact in bf16)
    bf16x8 qfA[2], qfB[2];
    #pragma unroll
    for (int s = 0; s < 2; ++s) {
        bf16x8 va = *(const bf16x8*)(Qb + kvbase + (size_t)(rA + w * 16 + ln) * 64 + s * 32 + koct * 8);
        bf16x8 vb = *(const bf16x8*)(Qb + kvbase + (size_t)(rB + w * 16 + ln) * 64 + s * 32 + koct * 8);
        #pragma unroll
        for (int j = 0; j < 8; ++j) {
            va[j] = (short)f2bf(bf2f((unsigned short)va[j]) * 0.125f);
            vb[j] = (short)f2bf(bf2f((unsigned short)vb[j]) * 0.125f);
        }
        qfA[s] = va; qfB[s] = vb;
    }

    f32x4 aoA[4], aoB[4];
    float mA[4], lA[4], mB[4], lB[4];
    #pragma unroll
    for (int r = 0; r < 4; ++r) { mA[r] = mB[r] = -INFINITY; lA[r] = lB[r] = 0.f; }
    #pragma unroll
    for (int nf = 0; nf < 4; ++nf) { aoA[nf] = f32x4{0.f,0.f,0.f,0.f}; aoB[nf] = f32x4{0.f,0.f,0.f,0.f}; }

    const int kr = t >> 3;        // staging row, +32 for second instr
    const int sg = t & 7;         // 16B segment within 128B row
    const int kr2 = kr + 32;

    // prologue: stage kt=0 into buffer 0
    gl16(Kb + kvbase + (size_t)kr  * 64 + (sg ^ (kr  & 7)) * 8, (char*)&Ksh[0][0] + t * 16);
    gl16(Kb + kvbase + (size_t)kr2 * 64 + (sg ^ (kr2 & 7)) * 8, (char*)&Ksh[0][0] + (t + 256) * 16);
    gl16(Vt + vtbase + (size_t)kr  * S_LEN + (sg ^ (kr  & 7)) * 8, (char*)&Vsh[0][0] + t * 16);
    gl16(Vt + vtbase + (size_t)kr2 * S_LEN + (sg ^ (kr2 & 7)) * 8, (char*)&Vsh[0][0] + (t + 256) * 16);
    __syncthreads();   // drain -> buf0 visible

    char* pb = (char*)Psh + w * 2048;
    int cur = 0;

    for (int kt = 0; kt <= qtB; ++kt) {
        if (kt < qtB) {   // issue next tile's staging early (hides HBM latency)
            const int c1 = (kt + 1) * 64;
            gl16(Kb + kvbase + (size_t)(c1 + kr)  * 64 + (sg ^ (kr  & 7)) * 8, (char*)&Ksh[cur ^ 1][0] + t * 16);
            gl16(Kb + kvbase + (size_t)(c1 + kr2) * 64 + (sg ^ (kr2 & 7)) * 8, (char*)&Ksh[cur ^ 1][0] + (t + 256) * 16);
            gl16(Vt + vtbase + (size_t)kr  * S_LEN + c1 + (sg ^ (kr  & 7)) * 8, (char*)&Vsh[cur ^ 1][0] + t * 16);
            gl16(Vt + vtbase + (size_t)kr2 * S_LEN + c1 + (sg ^ (kr2 & 7)) * 8, (char*)&Vsh[cur ^ 1][0] + (t + 256) * 16);
        }

        const char* Ks = (const char*)&Ksh[cur][0];
        const char* Vs = (const char*)&Vsh[cur][0];

        process_tile(Ks, Vs, pb, qfB, aoB, mB, lB, ln, koct,
                     (kt == qtB) ? (w * 16 + koct * 4) : (1 << 30));
        if (kt <= qtA)
            process_tile(Ks, Vs, pb, qfA, aoA, mA, lA, ln, koct,
                         (kt == qtA) ? (w * 16 + koct * 4) : (1 << 30));

        __syncthreads();   // implicit vmcnt/lgkm drain: next buffer published
        cur ^= 1;
    }

    // ---- epilogue: Aot [b][s][h*64+dh] bf16, both tiles ----
    const int b = bh >> 4, h = bh & 15;
    #pragma unroll
    for (int r = 0; r < 4; ++r) {
        const float invA = 1.0f / lA[r];
        const float invB = 1.0f / lB[r];
        const int sA = rA + w * 16 + koct * 4 + r;
        const int sB = rB + w * 16 + koct * 4 + r;
        #pragma unroll
        for (int nf = 0; nf < 4; ++nf) {
            Aot[(size_t)(b * S_LEN + sA) * 1024 + h * 64 + nf * 16 + ln] = f2bf(aoA[nf][r] * invA);
            Aot[(size_t)(b * S_LEN + sB) * 1024 + h * 64 + nf * 16 + ln] = f2bf(aoB[nf][r] * invB);
        }
    }
}

// ---------------------------------------------------------------------------
extern "C" void kernel_launch(void* const* d_in, const int* in_sizes, int n_in,
                              void* d_out, int out_size, void* d_ws, size_t ws_size,
                              hipStream_t stream)
{
    const float* x  = (const float*)d_in[0];
    const float* wq = (const float*)d_in[1];
    const float* wk = (const float*)d_in[2];
    const float* wv = (const float*)d_in[3];
    const float* wo = (const float*)d_in[4];
    float* out = (float*)d_out;

    char* p = (char*)d_ws;
    unsigned short* Xb  = (unsigned short*)p;                          // 16 MB
    unsigned short* Wb  = (unsigned short*)(p + ((size_t)16 << 20));   // 6 MB [3072][1024]
    unsigned short* Wob = (unsigned short*)(p + ((size_t)22 << 20));   // 2 MB
    unsigned short* Qb  = (unsigned short*)(p + ((size_t)24 << 20));   // 16 MB [bh][s][64]
    unsigned short* Kb  = (unsigned short*)(p + ((size_t)40 << 20));   // 16 MB
    unsigned short* Vt  = (unsigned short*)(p + ((size_t)56 << 20));   // 16 MB [bh][dh][s]
    unsigned short* Aot = (unsigned short*)(p + ((size_t)72 << 20));   // 16 MB [b][s][1024]

    const int NX = 8192 * 1024;
    cast_f32_bf16<<<NX / 2048, 256, 0, stream>>>(x, Xb, NX);
    cast_w4<<<2048, 256, 0, stream>>>(wq, wk, wv, wo, Wb, Wob);

    gemm_bt<0><<<dim3(64, 24), 256, 0, stream>>>(Xb, Wb, Qb, Kb, Vt, nullptr);
    rope_kernel<<<16384, 256, 0, stream>>>((unsigned int*)Qb, (unsigned int*)Kb);
    attn_mfma<<<dim3(16, 64), 256, 0, stream>>>(Qb, Kb, Vt, Aot);
    gemm_bt<1><<<dim3(64, 8), 256, 0, stream>>>(Aot, Wob, nullptr, nullptr, nullptr, out);
}

// Round 9
// 293.338 us; speedup vs baseline: 6.4712x; 1.2583x over previous
//
#include <hip/hip_runtime.h>
#include <cmath>

// Causal MHSA on MI355X, bf16-MFMA, round 6 logic (pack2 fixed: manual RNE
// pack instead of __builtin_bit_cast of __hip_bfloat162, which isn't
// trivially copyable on this ROCm).
// Swapped QK^T (mfma(K,Q)) so each lane owns a P-row segment -> scalar m/l,
// 2-shfl reduces, vectorized b64 P-stores. XCD-grouped attn grid.

#define S_LEN 2048
#define NHEAD 16
#define DHEAD 64

typedef short bf16x8 __attribute__((ext_vector_type(8)));
typedef float f32x4  __attribute__((ext_vector_type(4)));

__device__ __forceinline__ float bf2f(unsigned short u) {
    unsigned x = ((unsigned)u) << 16;
    return __builtin_bit_cast(float, x);
}
__device__ __forceinline__ unsigned short f2bf(float f) {   // RNE
    unsigned u = __builtin_bit_cast(unsigned, f);
    unsigned r = u + 0x7fff + ((u >> 16) & 1);
    return (unsigned short)(r >> 16);
}
__device__ __forceinline__ unsigned pack2(float lo, float hi) {  // 2xf32 -> packed 2xbf16
    return (unsigned)f2bf(lo) | ((unsigned)f2bf(hi) << 16);
}
__device__ __forceinline__ void gl16(const void* g, void* l) {
    __builtin_amdgcn_global_load_lds(
        (const __attribute__((address_space(1))) unsigned int*)g,
        (__attribute__((address_space(3))) unsigned int*)l, 16, 0, 0);
}

// ---------------------------------------------------------------------------
// f32 -> bf16 cast, 8 elems/thread (for x)
// ---------------------------------------------------------------------------
__global__ void cast_f32_bf16(const float* __restrict__ in,
                              unsigned* __restrict__ out, int n)
{
    const int i = (blockIdx.x * 256 + threadIdx.x) * 8;
    if (i >= n) return;
    const float4 a = *(const float4*)(in + i);
    const float4 b = *(const float4*)(in + i + 4);
    uint4 o;
    o.x = pack2(a.x, a.y); o.y = pack2(a.z, a.w);
    o.z = pack2(b.x, b.y); o.w = pack2(b.z, b.w);
    *(uint4*)(out + i / 2) = o;
}

// Fused cast of wq/wk/wv/wo (1M elems each) in one launch.
__global__ void cast_w4(const float* __restrict__ wq, const float* __restrict__ wk,
                        const float* __restrict__ wv, const float* __restrict__ wo,
                        unsigned* __restrict__ Wb, unsigned* __restrict__ Wob)
{
    const int idx = blockIdx.x * 256 + threadIdx.x;     // 524288 total threads
    const int sel = idx >> 17;                          // 0..3 (131072 thr each)
    const int loc = idx & 131071;
    const float* src = (sel == 0) ? wq : (sel == 1) ? wk : (sel == 2) ? wv : wo;
    unsigned* dst = (sel == 3) ? Wob : Wb + (size_t)sel * 524288;
    const int i = loc * 8;
    const float4 a = *(const float4*)(src + i);
    const float4 b = *(const float4*)(src + i + 4);
    uint4 o;
    o.x = pack2(a.x, a.y); o.y = pack2(a.z, a.w);
    o.z = pack2(b.x, b.y); o.w = pack2(b.z, b.w);
    *(uint4*)(dst + i / 2) = o;
}

// ---------------------------------------------------------------------------
// NT GEMM, bf16 MFMA (m97 structure): C = A[M,1024] * B[N,1024]^T
// 128x128 tile, BK=32, 256 thr (4 waves 2x2), acc 4x4 frags of 16x16.
// MODE 0: QKV — scatter bf16 to Qb/Kb [bh][s][64] and Vt [bh][dh][2048].
// MODE 1: OUT — f32 store to Co[M][1024].
// ---------------------------------------------------------------------------
template <int MODE>
__global__ __launch_bounds__(256, 2) void gemm_bt(
    const unsigned short* __restrict__ A,
    const unsigned short* __restrict__ Bw,
    unsigned short* __restrict__ Qb,
    unsigned short* __restrict__ Kb,
    unsigned short* __restrict__ Vt,
    float* __restrict__ Co)
{
    __shared__ __align__(16) unsigned short As[128 * 32];
    __shared__ __align__(16) unsigned short Bs[128 * 32];

    const int t    = threadIdx.x;
    const int bm   = blockIdx.x * 128;
    const int bn   = blockIdx.y * 128;
    const int lane = t & 63, wv = t >> 6;
    const int wr   = wv >> 1, wc = wv & 1;
    const int ln   = lane & 15, ko = lane >> 4;

    f32x4 acc[4][4];
    #pragma unroll
    for (int i = 0; i < 4; ++i)
        #pragma unroll
        for (int j = 0; j < 4; ++j)
            acc[i][j] = f32x4{0.f, 0.f, 0.f, 0.f};

    const int ar  = t >> 2;          // 0..63
    const int asg = t & 3;           // 16B segment of a 64B row-chunk
    const unsigned short* aptr = A  + (size_t)(bm + ar) * 1024 + asg * 8;
    const unsigned short* bptr = Bw + (size_t)(bn + ar) * 1024 + asg * 8;

    for (int k0 = 0; k0 < 1024; k0 += 32) {
        __syncthreads();
        gl16(aptr + k0,               (char*)As + t * 16);
        gl16(aptr + k0 + 64 * 1024,   (char*)As + (t + 256) * 16);
        gl16(bptr + k0,               (char*)Bs + t * 16);
        gl16(bptr + k0 + 64 * 1024,   (char*)Bs + (t + 256) * 16);
        __syncthreads();

        bf16x8 af[4], bfr[4];
        #pragma unroll
        for (int i = 0; i < 4; ++i)
            af[i] = *(const bf16x8*)((const char*)As + (wr * 64 + i * 16 + ln) * 64 + ko * 16);
        #pragma unroll
        for (int j = 0; j < 4; ++j)
            bfr[j] = *(const bf16x8*)((const char*)Bs + (wc * 64 + j * 16 + ln) * 64 + ko * 16);
        #pragma unroll
        for (int i = 0; i < 4; ++i)
            #pragma unroll
            for (int j = 0; j < 4; ++j)
                acc[i][j] = __builtin_amdgcn_mfma_f32_16x16x32_bf16(af[i], bfr[j], acc[i][j], 0, 0, 0);
    }

    #pragma unroll
    for (int i = 0; i < 4; ++i) {
        const int mb = bm + wr * 64 + i * 16 + ko * 4;   // 4 consecutive rows mb..mb+3
        #pragma unroll
        for (int j = 0; j < 4; ++j) {
            const int n = bn + wc * 64 + j * 16 + ln;
            if constexpr (MODE == 0) {
                const int which = n >> 10, nh = n & 1023;
                const int h = nh >> 6, dh = nh & 63;
                const int bb = mb >> 11, s = mb & 2047;
                const int bh = bb * NHEAD + h;
                if (which == 2) {
                    uint2 pk;
                    pk.x = pack2(acc[i][j][0], acc[i][j][1]);
                    pk.y = pack2(acc[i][j][2], acc[i][j][3]);
                    *(uint2*)&Vt[((size_t)bh * 64 + dh) * 2048 + s] = pk;
                } else {
                    unsigned short* dst = which ? Kb : Qb;
                    #pragma unroll
                    for (int r = 0; r < 4; ++r)
                        dst[((size_t)bh * 2048 + (s + r)) * 64 + dh] = f2bf(acc[i][j][r]);
                }
            } else {
                #pragma unroll
                for (int r = 0; r < 4; ++r)
                    Co[(size_t)(mb + r) * 1024 + n] = acc[i][j][r];
            }
        }
    }
}

// ---------------------------------------------------------------------------
// RoPE in-place on bf16 Q,K ([bh][s][64], interleaved pairs)
// ---------------------------------------------------------------------------
__global__ void rope_kernel(unsigned int* __restrict__ Qb, unsigned int* __restrict__ Kb)
{
    const int idx  = blockIdx.x * 256 + threadIdx.x;  // 64*2048*32 pairs
    const int i    = idx & 31;
    const int srow = (idx >> 5) & 2047;

    const float inv = powf(10000.0f, -(float)i * (1.0f / 32.0f));
    const float ang = (float)srow * inv;
    float sn, cs;
    sincosf(ang, &sn, &cs);

    const unsigned q = Qb[idx];
    const unsigned k = Kb[idx];
    const float qx = bf2f((unsigned short)(q & 0xffff)), qy = bf2f((unsigned short)(q >> 16));
    const float kx = bf2f((unsigned short)(k & 0xffff)), ky = bf2f((unsigned short)(k >> 16));
    Qb[idx] = pack2(qx * cs - qy * sn, qx * sn + qy * cs);
    Kb[idx] = pack2(kx * cs - ky * sn, kx * sn + ky * cs);
}

// ---------------------------------------------------------------------------
// One 64-key tile for one 64-q tile, SWAPPED orientation:
// sv[nf] = mfma(K,Q): lane (ln,koct) holds P[q=w*16+ln][key=nf*16+koct*4+r].
// Row-softmax: 15 in-lane fmax + shfl_xor(16,32). P packed and stored as
// 4x ds_write_b64, key-contiguous, swizzled by (ln&7)<<4 — byte-identical
// layout to the old scalar writes, so PV's swizzled b128 reads are
// unchanged. ao rescale gets al via 4 lane-broadcasts.
// ---------------------------------------------------------------------------
__device__ __forceinline__ void process_tile(
    const char* __restrict__ Ks, const char* __restrict__ Vs, char* pb,
    const bf16x8 qf[2], f32x4 ao[4], float& m_i, float& l_i,
    int ln, int koct, int qrow, bool diag)
{
    // ---- QK^T (swapped): sv[nf][r] = P[qrow][nf*16+koct*4+r] ----
    f32x4 sv[4];
    #pragma unroll
    for (int nf = 0; nf < 4; ++nf) sv[nf] = f32x4{0.f, 0.f, 0.f, 0.f};
    #pragma unroll
    for (int s = 0; s < 2; ++s) {
        #pragma unroll
        for (int nf = 0; nf < 4; ++nf) {
            const int key = nf * 16 + ln;
            const bf16x8 kf = *(const bf16x8*)(Ks + key * 128 + (((s * 4 + koct) ^ (key & 7)) * 16));
            sv[nf] = __builtin_amdgcn_mfma_f32_16x16x32_bf16(kf, qf[s], sv[nf], 0, 0, 0);
        }
    }

    if (diag) {   // causal mask: key > qrow
        #pragma unroll
        for (int nf = 0; nf < 4; ++nf) {
            #pragma unroll
            for (int r = 0; r < 4; ++r)
                if (nf * 16 + koct * 4 + r > qrow) sv[nf][r] = -INFINITY;
        }
    }

    // ---- online softmax, one row per lane ----
    float mx = sv[0][0];
    #pragma unroll
    for (int nf = 0; nf < 4; ++nf)
        #pragma unroll
        for (int r = 0; r < 4; ++r) mx = fmaxf(mx, sv[nf][r]);
    mx = fmaxf(mx, __shfl_xor(mx, 16));
    mx = fmaxf(mx, __shfl_xor(mx, 32));
    const float mn = fmaxf(m_i, mx);
    const float al = __expf(m_i - mn);
    m_i = mn;
    float sum = 0.f;
    #pragma unroll
    for (int nf = 0; nf < 4; ++nf)
        #pragma unroll
        for (int r = 0; r < 4; ++r) {
            const float pv = __expf(sv[nf][r] - mn);
            sv[nf][r] = pv;
            sum += pv;
        }
    sum += __shfl_xor(sum, 16);
    sum += __shfl_xor(sum, 32);
    l_i = l_i * al + sum;

    // ---- rescale ao (rows q = koct*4+r) ----
    float alr[4];
    #pragma unroll
    for (int r = 0; r < 4; ++r) alr[r] = __shfl(al, koct * 4 + r);
    #pragma unroll
    for (int nf = 0; nf < 4; ++nf)
        #pragma unroll
        for (int r = 0; r < 4; ++r)
            ao[nf][r] *= alr[r];

    // ---- P -> per-wave LDS: 4x b64, key-contiguous packs ----
    #pragma unroll
    for (int nf = 0; nf < 4; ++nf) {
        uint2 pk;
        pk.x = pack2(sv[nf][0], sv[nf][1]);
        pk.y = pack2(sv[nf][2], sv[nf][3]);
        *(uint2*)(pb + ln * 128 + ((nf * 32 + koct * 8) ^ ((ln & 7) << 4))) = pk;
    }
    // wave-private P; same-wave lgkm ordering handled by compiler

    // ---- PV: O[16q][64dh] += P[16,64] * V[64,64] ----
    #pragma unroll
    for (int s2 = 0; s2 < 2; ++s2) {
        const bf16x8 pa = *(const bf16x8*)(pb + ln * 128 + (((s2 * 4 + koct) ^ (ln & 7)) * 16));
        #pragma unroll
        for (int nf = 0; nf < 4; ++nf) {
            const int dh = nf * 16 + ln;
            const bf16x8 vf = *(const bf16x8*)(Vs + dh * 128 + (((s2 * 4 + koct) ^ (dh & 7)) * 16));
            ao[nf] = __builtin_amdgcn_mfma_f32_16x16x32_bf16(pa, vf, ao[nf], 0, 0, 0);
        }
    }
}

// ---------------------------------------------------------------------------
// MFMA flash attention, causal, PAIRED q-tiles (qtA, 31-qtA): 33 tiles/block.
// K/V double-buffered, next tile staged before computing current.
// Grid = 1024 linear, relabeled so all 16 blocks of a bh share one XCD
// (XCD = bid%8): 8 bh x 512KB K/V = 4MB = one XCD L2.
// ---------------------------------------------------------------------------
__global__ __launch_bounds__(256, 3) void attn_mfma(
    const unsigned short* __restrict__ Qb,
    const unsigned short* __restrict__ Kb,
    const unsigned short* __restrict__ Vt,
    unsigned short* __restrict__ Aot)
{
    __shared__ __align__(16) unsigned short Ksh[2][64 * 64];
    __shared__ __align__(16) unsigned short Vsh[2][64 * 64];
    __shared__ __align__(16) unsigned short Psh[4 * 16 * 64];

    const int t    = threadIdx.x;
    const int lane = t & 63, w = t >> 6;
    const int ln   = lane & 15, koct = lane >> 4;
    const int bid  = blockIdx.x;               // 0..1023
    const int qtA  = (bid >> 3) & 15;          // 0..15
    const int qtB  = 31 - qtA;                 // 31..16
    const int bh   = (bid & 7) + 8 * (bid >> 7);
    const int rA   = qtA * 64, rB = qtB * 64;
    const size_t kvbase = (size_t)bh * S_LEN * DHEAD;
    const size_t vtbase = (size_t)bh * DHEAD * S_LEN;

    // Q fragments for both tiles, pre-scaled by 1/8 (exact in bf16)
    bf16x8 qfA[2], qfB[2];
    #pragma unroll
    for (int s = 0; s < 2; ++s) {
        bf16x8 va = *(const bf16x8*)(Qb + kvbase + (size_t)(rA + w * 16 + ln) * 64 + s * 32 + koct * 8);
        bf16x8 vb = *(const bf16x8*)(Qb + kvbase + (size_t)(rB + w * 16 + ln) * 64 + s * 32 + koct * 8);
        #pragma unroll
        for (int j = 0; j < 8; ++j) {
            va[j] = (short)f2bf(bf2f((unsigned short)va[j]) * 0.125f);
            vb[j] = (short)f2bf(bf2f((unsigned short)vb[j]) * 0.125f);
        }
        qfA[s] = va; qfB[s] = vb;
    }

    f32x4 aoA[4], aoB[4];
    float mA = -INFINITY, lA = 0.f, mB = -INFINITY, lB = 0.f;
    #pragma unroll
    for (int nf = 0; nf < 4; ++nf) { aoA[nf] = f32x4{0.f,0.f,0.f,0.f}; aoB[nf] = f32x4{0.f,0.f,0.f,0.f}; }

    const int kr = t >> 3;        // staging row, +32 for second instr
    const int sg = t & 7;         // 16B segment within 128B row
    const int kr2 = kr + 32;
    const int qrow = w * 16 + ln; // this lane's softmax row (within 64-tile)

    // prologue: stage kt=0 into buffer 0
    gl16(Kb + kvbase + (size_t)kr  * 64 + (sg ^ (kr  & 7)) * 8, (char*)&Ksh[0][0] + t * 16);
    gl16(Kb + kvbase + (size_t)kr2 * 64 + (sg ^ (kr2 & 7)) * 8, (char*)&Ksh[0][0] + (t + 256) * 16);
    gl16(Vt + vtbase + (size_t)kr  * S_LEN + (sg ^ (kr  & 7)) * 8, (char*)&Vsh[0][0] + t * 16);
    gl16(Vt + vtbase + (size_t)kr2 * S_LEN + (sg ^ (kr2 & 7)) * 8, (char*)&Vsh[0][0] + (t + 256) * 16);
    __syncthreads();   // drain -> buf0 visible

    char* pb = (char*)Psh + w * 2048;
    int cur = 0;

    for (int kt = 0; kt <= qtB; ++kt) {
        if (kt < qtB) {   // issue next tile's staging early (hides HBM latency)
            const int c1 = (kt + 1) * 64;
            gl16(Kb + kvbase + (size_t)(c1 + kr)  * 64 + (sg ^ (kr  & 7)) * 8, (char*)&Ksh[cur ^ 1][0] + t * 16);
            gl16(Kb + kvbase + (size_t)(c1 + kr2) * 64 + (sg ^ (kr2 & 7)) * 8, (char*)&Ksh[cur ^ 1][0] + (t + 256) * 16);
            gl16(Vt + vtbase + (size_t)kr  * S_LEN + c1 + (sg ^ (kr  & 7)) * 8, (char*)&Vsh[cur ^ 1][0] + t * 16);
            gl16(Vt + vtbase + (size_t)kr2 * S_LEN + c1 + (sg ^ (kr2 & 7)) * 8, (char*)&Vsh[cur ^ 1][0] + (t + 256) * 16);
        }

        const char* Ks = (const char*)&Ksh[cur][0];
        const char* Vs = (const char*)&Vsh[cur][0];

        process_tile(Ks, Vs, pb, qfB, aoB, mB, lB, ln, koct, qrow, kt == qtB);
        if (kt <= qtA)
            process_tile(Ks, Vs, pb, qfA, aoA, mA, lA, ln, koct, qrow, kt == qtA);

        __syncthreads();   // implicit vmcnt/lgkm drain: next buffer published
        cur ^= 1;
    }

    // ---- epilogue: Aot [b][s][h*64+dh] bf16, both tiles ----
    const int b = bh >> 4, h = bh & 15;
    float lAr[4], lBr[4];
    #pragma unroll
    for (int r = 0; r < 4; ++r) {
        lAr[r] = __shfl(lA, koct * 4 + r);
        lBr[r] = __shfl(lB, koct * 4 + r);
    }
    #pragma unroll
    for (int r = 0; r < 4; ++r) {
        const float invA = 1.0f / lAr[r];
        const float invB = 1.0f / lBr[r];
        const int sA = rA + w * 16 + koct * 4 + r;
        const int sB = rB + w * 16 + koct * 4 + r;
        #pragma unroll
        for (int nf = 0; nf < 4; ++nf) {
            Aot[(size_t)(b * S_LEN + sA) * 1024 + h * 64 + nf * 16 + ln] = f2bf(aoA[nf][r] * invA);
            Aot[(size_t)(b * S_LEN + sB) * 1024 + h * 64 + nf * 16 + ln] = f2bf(aoB[nf][r] * invB);
        }
    }
}

// ---------------------------------------------------------------------------
extern "C" void kernel_launch(void* const* d_in, const int* in_sizes, int n_in,
                              void* d_out, int out_size, void* d_ws, size_t ws_size,
                              hipStream_t stream)
{
    const float* x  = (const float*)d_in[0];
    const float* wq = (const float*)d_in[1];
    const float* wk = (const float*)d_in[2];
    const float* wv = (const float*)d_in[3];
    const float* wo = (const float*)d_in[4];
    float* out = (float*)d_out;

    char* p = (char*)d_ws;
    unsigned short* Xb  = (unsigned short*)p;                          // 16 MB
    unsigned short* Wb  = (unsigned short*)(p + ((size_t)16 << 20));   // 6 MB [3072][1024]
    unsigned short* Wob = (unsigned short*)(p + ((size_t)22 << 20));   // 2 MB
    unsigned short* Qb  = (unsigned short*)(p + ((size_t)24 << 20));   // 16 MB [bh][s][64]
    unsigned short* Kb  = (unsigned short*)(p + ((size_t)40 << 20));   // 16 MB
    unsigned short* Vt  = (unsigned short*)(p + ((size_t)56 << 20));   // 16 MB [bh][dh][s]
    unsigned short* Aot = (unsigned short*)(p + ((size_t)72 << 20));   // 16 MB [b][s][1024]

    const int NX = 8192 * 1024;
    cast_f32_bf16<<<NX / 2048, 256, 0, stream>>>(x, (unsigned*)Xb, NX);
    cast_w4<<<2048, 256, 0, stream>>>(wq, wk, wv, wo, (unsigned*)Wb, (unsigned*)Wob);

    gemm_bt<0><<<dim3(64, 24), 256, 0, stream>>>(Xb, Wb, Qb, Kb, Vt, nullptr);
    rope_kernel<<<16384, 256, 0, stream>>>((unsigned int*)Qb, (unsigned int*)Kb);
    attn_mfma<<<1024, 256, 0, stream>>>(Qb, Kb, Vt, Aot);
    gemm_bt<1><<<dim3(64, 8), 256, 0, stream>>>(Aot, Wob, nullptr, nullptr, nullptr, out);
}

// Round 10
// 293.066 us; speedup vs baseline: 6.4772x; 1.0009x over previous
//
#include <hip/hip_runtime.h>
#include <cmath>

// Causal MHSA on MI355X, bf16-MFMA, round 10.
// Changes vs round 9: (a) GEMM double-buffered LDS staging (issue-early gl16,
// single barrier per 32-chunk, launch_bounds(256,3)); (b) attn defer-max
// (T13, THR=8): skip al/rescale when wave-uniform max growth is small.

#define S_LEN 2048
#define NHEAD 16
#define DHEAD 64

typedef short bf16x8 __attribute__((ext_vector_type(8)));
typedef float f32x4  __attribute__((ext_vector_type(4)));

__device__ __forceinline__ float bf2f(unsigned short u) {
    unsigned x = ((unsigned)u) << 16;
    return __builtin_bit_cast(float, x);
}
__device__ __forceinline__ unsigned short f2bf(float f) {   // RNE
    unsigned u = __builtin_bit_cast(unsigned, f);
    unsigned r = u + 0x7fff + ((u >> 16) & 1);
    return (unsigned short)(r >> 16);
}
__device__ __forceinline__ unsigned pack2(float lo, float hi) {  // 2xf32 -> packed 2xbf16
    return (unsigned)f2bf(lo) | ((unsigned)f2bf(hi) << 16);
}
__device__ __forceinline__ void gl16(const void* g, void* l) {
    __builtin_amdgcn_global_load_lds(
        (const __attribute__((address_space(1))) unsigned int*)g,
        (__attribute__((address_space(3))) unsigned int*)l, 16, 0, 0);
}

// ---------------------------------------------------------------------------
// f32 -> bf16 cast, 8 elems/thread (for x)
// ---------------------------------------------------------------------------
__global__ void cast_f32_bf16(const float* __restrict__ in,
                              unsigned* __restrict__ out, int n)
{
    const int i = (blockIdx.x * 256 + threadIdx.x) * 8;
    if (i >= n) return;
    const float4 a = *(const float4*)(in + i);
    const float4 b = *(const float4*)(in + i + 4);
    uint4 o;
    o.x = pack2(a.x, a.y); o.y = pack2(a.z, a.w);
    o.z = pack2(b.x, b.y); o.w = pack2(b.z, b.w);
    *(uint4*)(out + i / 2) = o;
}

// Fused cast of wq/wk/wv/wo (1M elems each) in one launch.
__global__ void cast_w4(const float* __restrict__ wq, const float* __restrict__ wk,
                        const float* __restrict__ wv, const float* __restrict__ wo,
                        unsigned* __restrict__ Wb, unsigned* __restrict__ Wob)
{
    const int idx = blockIdx.x * 256 + threadIdx.x;     // 524288 total threads
    const int sel = idx >> 17;                          // 0..3 (131072 thr each)
    const int loc = idx & 131071;
    const float* src = (sel == 0) ? wq : (sel == 1) ? wk : (sel == 2) ? wv : wo;
    unsigned* dst = (sel == 3) ? Wob : Wb + (size_t)sel * 524288;
    const int i = loc * 8;
    const float4 a = *(const float4*)(src + i);
    const float4 b = *(const float4*)(src + i + 4);
    uint4 o;
    o.x = pack2(a.x, a.y); o.y = pack2(a.z, a.w);
    o.z = pack2(b.x, b.y); o.w = pack2(b.z, b.w);
    *(uint4*)(dst + i / 2) = o;
}

// ---------------------------------------------------------------------------
// NT GEMM, bf16 MFMA, double-buffered: C = A[M,1024] * B[N,1024]^T
// 128x128 tile, BK=32 chunks x2 per iter, 256 thr (4 waves 2x2), 4x4 frags.
// Staging for chunk c+1 is issued BEFORE computing chunk c; one barrier per
// chunk (its implicit vmcnt drain publishes the prefetch) — same verified
// pattern as attn_mfma. LDS 32KB -> 3 blocks/CU (launch_bounds 256,3).
// MODE 0: QKV — scatter bf16 to Qb/Kb [bh][s][64] and Vt [bh][dh][2048].
// MODE 1: OUT — f32 store to Co[M][1024].
// ---------------------------------------------------------------------------
template <int MODE>
__global__ __launch_bounds__(256, 3) void gemm_bt(
    const unsigned short* __restrict__ A,
    const unsigned short* __restrict__ Bw,
    unsigned short* __restrict__ Qb,
    unsigned short* __restrict__ Kb,
    unsigned short* __restrict__ Vt,
    float* __restrict__ Co)
{
    __shared__ __align__(16) unsigned short As[2][128 * 32];
    __shared__ __align__(16) unsigned short Bs[2][128 * 32];

    const int t    = threadIdx.x;
    const int bm   = blockIdx.x * 128;
    const int bn   = blockIdx.y * 128;
    const int lane = t & 63, wv = t >> 6;
    const int wr   = wv >> 1, wc = wv & 1;
    const int ln   = lane & 15, ko = lane >> 4;

    f32x4 acc[4][4];
    #pragma unroll
    for (int i = 0; i < 4; ++i)
        #pragma unroll
        for (int j = 0; j < 4; ++j)
            acc[i][j] = f32x4{0.f, 0.f, 0.f, 0.f};

    const int ar  = t >> 2;          // 0..63
    const int asg = t & 3;           // 16B segment of a 64B row-chunk
    const unsigned short* aptr = A  + (size_t)(bm + ar) * 1024 + asg * 8;
    const unsigned short* bptr = Bw + (size_t)(bn + ar) * 1024 + asg * 8;

    #define STAGE(k0, buf)                                                          \
        do {                                                                        \
            gl16(aptr + (k0),             (char*)&As[buf][0] + t * 16);             \
            gl16(aptr + (k0) + 64 * 1024, (char*)&As[buf][0] + (t + 256) * 16);     \
            gl16(bptr + (k0),             (char*)&Bs[buf][0] + t * 16);             \
            gl16(bptr + (k0) + 64 * 1024, (char*)&Bs[buf][0] + (t + 256) * 16);     \
        } while (0)

    #define COMPUTE(buf)                                                            \
        do {                                                                        \
            bf16x8 af[4], bfr[4];                                                   \
            _Pragma("unroll")                                                       \
            for (int i = 0; i < 4; ++i)                                             \
                af[i] = *(const bf16x8*)((const char*)&As[buf][0] +                 \
                         (wr * 64 + i * 16 + ln) * 64 + ko * 16);                   \
            _Pragma("unroll")                                                       \
            for (int j = 0; j < 4; ++j)                                             \
                bfr[j] = *(const bf16x8*)((const char*)&Bs[buf][0] +                \
                         (wc * 64 + j * 16 + ln) * 64 + ko * 16);                   \
            _Pragma("unroll")                                                       \
            for (int i = 0; i < 4; ++i)                                             \
                _Pragma("unroll")                                                   \
                for (int j = 0; j < 4; ++j)                                         \
                    acc[i][j] = __builtin_amdgcn_mfma_f32_16x16x32_bf16(            \
                        af[i], bfr[j], acc[i][j], 0, 0, 0);                         \
        } while (0)

    STAGE(0, 0);
    __syncthreads();

    for (int k0 = 0; k0 < 1024; k0 += 64) {
        if (k0 + 32 < 1024) STAGE(k0 + 32, 1);
        COMPUTE(0);
        __syncthreads();
        if (k0 + 64 < 1024) STAGE(k0 + 64, 0);
        COMPUTE(1);
        __syncthreads();
    }
    #undef STAGE
    #undef COMPUTE

    #pragma unroll
    for (int i = 0; i < 4; ++i) {
        const int mb = bm + wr * 64 + i * 16 + ko * 4;   // 4 consecutive rows mb..mb+3
        #pragma unroll
        for (int j = 0; j < 4; ++j) {
            const int n = bn + wc * 64 + j * 16 + ln;
            if constexpr (MODE == 0) {
                const int which = n >> 10, nh = n & 1023;
                const int h = nh >> 6, dh = nh & 63;
                const int bb = mb >> 11, s = mb & 2047;
                const int bh = bb * NHEAD + h;
                if (which == 2) {
                    uint2 pk;
                    pk.x = pack2(acc[i][j][0], acc[i][j][1]);
                    pk.y = pack2(acc[i][j][2], acc[i][j][3]);
                    *(uint2*)&Vt[((size_t)bh * 64 + dh) * 2048 + s] = pk;
                } else {
                    unsigned short* dst = which ? Kb : Qb;
                    #pragma unroll
                    for (int r = 0; r < 4; ++r)
                        dst[((size_t)bh * 2048 + (s + r)) * 64 + dh] = f2bf(acc[i][j][r]);
                }
            } else {
                #pragma unroll
                for (int r = 0; r < 4; ++r)
                    Co[(size_t)(mb + r) * 1024 + n] = acc[i][j][r];
            }
        }
    }
}

// ---------------------------------------------------------------------------
// RoPE in-place on bf16 Q,K ([bh][s][64], interleaved pairs)
// ---------------------------------------------------------------------------
__global__ void rope_kernel(unsigned int* __restrict__ Qb, unsigned int* __restrict__ Kb)
{
    const int idx  = blockIdx.x * 256 + threadIdx.x;  // 64*2048*32 pairs
    const int i    = idx & 31;
    const int srow = (idx >> 5) & 2047;

    const float inv = powf(10000.0f, -(float)i * (1.0f / 32.0f));
    const float ang = (float)srow * inv;
    float sn, cs;
    sincosf(ang, &sn, &cs);

    const unsigned q = Qb[idx];
    const unsigned k = Kb[idx];
    const float qx = bf2f((unsigned short)(q & 0xffff)), qy = bf2f((unsigned short)(q >> 16));
    const float kx = bf2f((unsigned short)(k & 0xffff)), ky = bf2f((unsigned short)(k >> 16));
    Qb[idx] = pack2(qx * cs - qy * sn, qx * sn + qy * cs);
    Kb[idx] = pack2(kx * cs - ky * sn, kx * sn + ky * cs);
}

// ---------------------------------------------------------------------------
// One 64-key tile for one 64-q tile, swapped orientation + defer-max (T13):
// sv[nf] = mfma(K,Q): lane (ln,koct) holds P[q=w*16+ln][key=nf*16+koct*4+r].
// When __all(mx <= m+8) keep old max (skip al + ao-rescale); P bounded e^8.
// ---------------------------------------------------------------------------
__device__ __forceinline__ void process_tile(
    const char* __restrict__ Ks, const char* __restrict__ Vs, char* pb,
    const bf16x8 qf[2], f32x4 ao[4], float& m_i, float& l_i,
    int ln, int koct, int qrow, bool diag)
{
    // ---- QK^T (swapped): sv[nf][r] = P[qrow][nf*16+koct*4+r] ----
    f32x4 sv[4];
    #pragma unroll
    for (int nf = 0; nf < 4; ++nf) sv[nf] = f32x4{0.f, 0.f, 0.f, 0.f};
    #pragma unroll
    for (int s = 0; s < 2; ++s) {
        #pragma unroll
        for (int nf = 0; nf < 4; ++nf) {
            const int key = nf * 16 + ln;
            const bf16x8 kf = *(const bf16x8*)(Ks + key * 128 + (((s * 4 + koct) ^ (key & 7)) * 16));
            sv[nf] = __builtin_amdgcn_mfma_f32_16x16x32_bf16(kf, qf[s], sv[nf], 0, 0, 0);
        }
    }

    if (diag) {   // causal mask: key > qrow
        #pragma unroll
        for (int nf = 0; nf < 4; ++nf) {
            #pragma unroll
            for (int r = 0; r < 4; ++r)
                if (nf * 16 + koct * 4 + r > qrow) sv[nf][r] = -INFINITY;
        }
    }

    // ---- online softmax, one row per lane; defer-max THR=8 ----
    float mx = sv[0][0];
    #pragma unroll
    for (int nf = 0; nf < 4; ++nf)
        #pragma unroll
        for (int r = 0; r < 4; ++r) mx = fmaxf(mx, sv[nf][r]);
    mx = fmaxf(mx, __shfl_xor(mx, 16));
    mx = fmaxf(mx, __shfl_xor(mx, 32));

    if (!__all(mx <= m_i + 8.0f)) {      // growth too large -> rescale
        const float mn = fmaxf(m_i, mx);
        const float al = __expf(m_i - mn);
        m_i = mn;
        l_i *= al;
        float alr[4];
        #pragma unroll
        for (int r = 0; r < 4; ++r) alr[r] = __shfl(al, koct * 4 + r);
        #pragma unroll
        for (int nf = 0; nf < 4; ++nf)
            #pragma unroll
            for (int r = 0; r < 4; ++r)
                ao[nf][r] *= alr[r];
    }

    float sum = 0.f;
    #pragma unroll
    for (int nf = 0; nf < 4; ++nf)
        #pragma unroll
        for (int r = 0; r < 4; ++r) {
            const float pv = __expf(sv[nf][r] - m_i);
            sv[nf][r] = pv;
            sum += pv;
        }
    sum += __shfl_xor(sum, 16);
    sum += __shfl_xor(sum, 32);
    l_i += sum;

    // ---- P -> per-wave LDS: 4x b64, key-contiguous packs ----
    #pragma unroll
    for (int nf = 0; nf < 4; ++nf) {
        uint2 pk;
        pk.x = pack2(sv[nf][0], sv[nf][1]);
        pk.y = pack2(sv[nf][2], sv[nf][3]);
        *(uint2*)(pb + ln * 128 + ((nf * 32 + koct * 8) ^ ((ln & 7) << 4))) = pk;
    }
    // wave-private P; same-wave lgkm ordering handled by compiler

    // ---- PV: O[16q][64dh] += P[16,64] * V[64,64] ----
    #pragma unroll
    for (int s2 = 0; s2 < 2; ++s2) {
        const bf16x8 pa = *(const bf16x8*)(pb + ln * 128 + (((s2 * 4 + koct) ^ (ln & 7)) * 16));
        #pragma unroll
        for (int nf = 0; nf < 4; ++nf) {
            const int dh = nf * 16 + ln;
            const bf16x8 vf = *(const bf16x8*)(Vs + dh * 128 + (((s2 * 4 + koct) ^ (dh & 7)) * 16));
            ao[nf] = __builtin_amdgcn_mfma_f32_16x16x32_bf16(pa, vf, ao[nf], 0, 0, 0);
        }
    }
}

// ---------------------------------------------------------------------------
// MFMA flash attention, causal, PAIRED q-tiles (qtA, 31-qtA): 33 tiles/block.
// K/V double-buffered, next tile staged before computing current.
// Grid = 1024 linear, relabeled so all 16 blocks of a bh share one XCD
// (XCD = bid%8): 8 bh x 512KB K/V = 4MB = one XCD L2.
// ---------------------------------------------------------------------------
__global__ __launch_bounds__(256, 3) void attn_mfma(
    const unsigned short* __restrict__ Qb,
    const unsigned short* __restrict__ Kb,
    const unsigned short* __restrict__ Vt,
    unsigned short* __restrict__ Aot)
{
    __shared__ __align__(16) unsigned short Ksh[2][64 * 64];
    __shared__ __align__(16) unsigned short Vsh[2][64 * 64];
    __shared__ __align__(16) unsigned short Psh[4 * 16 * 64];

    const int t    = threadIdx.x;
    const int lane = t & 63, w = t >> 6;
    const int ln   = lane & 15, koct = lane >> 4;
    const int bid  = blockIdx.x;               // 0..1023
    const int qtA  = (bid >> 3) & 15;          // 0..15
    const int qtB  = 31 - qtA;                 // 31..16
    const int bh   = (bid & 7) + 8 * (bid >> 7);
    const int rA   = qtA * 64, rB = qtB * 64;
    const size_t kvbase = (size_t)bh * S_LEN * DHEAD;
    const size_t vtbase = (size_t)bh * DHEAD * S_LEN;

    // Q fragments for both tiles, pre-scaled by 1/8 (exact in bf16)
    bf16x8 qfA[2], qfB[2];
    #pragma unroll
    for (int s = 0; s < 2; ++s) {
        bf16x8 va = *(const bf16x8*)(Qb + kvbase + (size_t)(rA + w * 16 + ln) * 64 + s * 32 + koct * 8);
        bf16x8 vb = *(const bf16x8*)(Qb + kvbase + (size_t)(rB + w * 16 + ln) * 64 + s * 32 + koct * 8);
        #pragma unroll
        for (int j = 0; j < 8; ++j) {
            va[j] = (short)f2bf(bf2f((unsigned short)va[j]) * 0.125f);
            vb[j] = (short)f2bf(bf2f((unsigned short)vb[j]) * 0.125f);
        }
        qfA[s] = va; qfB[s] = vb;
    }

    f32x4 aoA[4], aoB[4];
    float mA = -INFINITY, lA = 0.f, mB = -INFINITY, lB = 0.f;
    #pragma unroll
    for (int nf = 0; nf < 4; ++nf) { aoA[nf] = f32x4{0.f,0.f,0.f,0.f}; aoB[nf] = f32x4{0.f,0.f,0.f,0.f}; }

    const int kr = t >> 3;        // staging row, +32 for second instr
    const int sg = t & 7;         // 16B segment within 128B row
    const int kr2 = kr + 32;
    const int qrow = w * 16 + ln; // this lane's softmax row (within 64-tile)

    // prologue: stage kt=0 into buffer 0
    gl16(Kb + kvbase + (size_t)kr  * 64 + (sg ^ (kr  & 7)) * 8, (char*)&Ksh[0][0] + t * 16);
    gl16(Kb + kvbase + (size_t)kr2 * 64 + (sg ^ (kr2 & 7)) * 8, (char*)&Ksh[0][0] + (t + 256) * 16);
    gl16(Vt + vtbase + (size_t)kr  * S_LEN + (sg ^ (kr  & 7)) * 8, (char*)&Vsh[0][0] + t * 16);
    gl16(Vt + vtbase + (size_t)kr2 * S_LEN + (sg ^ (kr2 & 7)) * 8, (char*)&Vsh[0][0] + (t + 256) * 16);
    __syncthreads();   // drain -> buf0 visible

    char* pb = (char*)Psh + w * 2048;
    int cur = 0;

    for (int kt = 0; kt <= qtB; ++kt) {
        if (kt < qtB) {   // issue next tile's staging early (hides HBM latency)
            const int c1 = (kt + 1) * 64;
            gl16(Kb + kvbase + (size_t)(c1 + kr)  * 64 + (sg ^ (kr  & 7)) * 8, (char*)&Ksh[cur ^ 1][0] + t * 16);
            gl16(Kb + kvbase + (size_t)(c1 + kr2) * 64 + (sg ^ (kr2 & 7)) * 8, (char*)&Ksh[cur ^ 1][0] + (t + 256) * 16);
            gl16(Vt + vtbase + (size_t)kr  * S_LEN + c1 + (sg ^ (kr  & 7)) * 8, (char*)&Vsh[cur ^ 1][0] + t * 16);
            gl16(Vt + vtbase + (size_t)kr2 * S_LEN + c1 + (sg ^ (kr2 & 7)) * 8, (char*)&Vsh[cur ^ 1][0] + (t + 256) * 16);
        }

        const char* Ks = (const char*)&Ksh[cur][0];
        const char* Vs = (const char*)&Vsh[cur][0];

        process_tile(Ks, Vs, pb, qfB, aoB, mB, lB, ln, koct, qrow, kt == qtB);
        if (kt <= qtA)
            process_tile(Ks, Vs, pb, qfA, aoA, mA, lA, ln, koct, qrow, kt == qtA);

        __syncthreads();   // implicit vmcnt/lgkm drain: next buffer published
        cur ^= 1;
    }

    // ---- epilogue: Aot [b][s][h*64+dh] bf16, both tiles ----
    const int b = bh >> 4, h = bh & 15;
    float lAr[4], lBr[4];
    #pragma unroll
    for (int r = 0; r < 4; ++r) {
        lAr[r] = __shfl(lA, koct * 4 + r);
        lBr[r] = __shfl(lB, koct * 4 + r);
    }
    #pragma unroll
    for (int r = 0; r < 4; ++r) {
        const float invA = 1.0f / lAr[r];
        const float invB = 1.0f / lBr[r];
        const int sA = rA + w * 16 + koct * 4 + r;
        const int sB = rB + w * 16 + koct * 4 + r;
        #pragma unroll
        for (int nf = 0; nf < 4; ++nf) {
            Aot[(size_t)(b * S_LEN + sA) * 1024 + h * 64 + nf * 16 + ln] = f2bf(aoA[nf][r] * invA);
            Aot[(size_t)(b * S_LEN + sB) * 1024 + h * 64 + nf * 16 + ln] = f2bf(aoB[nf][r] * invB);
        }
    }
}

// ---------------------------------------------------------------------------
extern "C" void kernel_launch(void* const* d_in, const int* in_sizes, int n_in,
                              void* d_out, int out_size, void* d_ws, size_t ws_size,
                              hipStream_t stream)
{
    const float* x  = (const float*)d_in[0];
    const float* wq = (const float*)d_in[1];
    const float* wk = (const float*)d_in[2];
    const float* wv = (const float*)d_in[3];
    const float* wo = (const float*)d_in[4];
    float* out = (float*)d_out;

    char* p = (char*)d_ws;
    unsigned short* Xb  = (unsigned short*)p;                          // 16 MB
    unsigned short* Wb  = (unsigned short*)(p + ((size_t)16 << 20));   // 6 MB [3072][1024]
    unsigned short* Wob = (unsigned short*)(p + ((size_t)22 << 20));   // 2 MB
    unsigned short* Qb  = (unsigned short*)(p + ((size_t)24 << 20));   // 16 MB [bh][s][64]
    unsigned short* Kb  = (unsigned short*)(p + ((size_t)40 << 20));   // 16 MB
    unsigned short* Vt  = (unsigned short*)(p + ((size_t)56 << 20));   // 16 MB [bh][dh][s]
    unsigned short* Aot = (unsigned short*)(p + ((size_t)72 << 20));   // 16 MB [b][s][1024]

    const int NX = 8192 * 1024;
    cast_f32_bf16<<<NX / 2048, 256, 0, stream>>>(x, (unsigned*)Xb, NX);
    cast_w4<<<2048, 256, 0, stream>>>(wq, wk, wv, wo, (unsigned*)Wb, (unsigned*)Wob);

    gemm_bt<0><<<dim3(64, 24), 256, 0, stream>>>(Xb, Wb, Qb, Kb, Vt, nullptr);
    rope_kernel<<<16384, 256, 0, stream>>>((unsigned int*)Qb, (unsigned int*)Kb);
    attn_mfma<<<1024, 256, 0, stream>>>(Qb, Kb, Vt, Aot);
    gemm_bt<1><<<dim3(64, 8), 256, 0, stream>>>(Aot, Wob, nullptr, nullptr, nullptr, out);
}

// Round 11
// 257.762 us; speedup vs baseline: 7.3643x; 1.1370x over previous
//
#include <hip/hip_runtime.h>
#include <cmath>

// Causal MHSA on MI355X, bf16-MFMA, round 11.
// Changes vs round 10: (a) attn processes FOUR q-tiles per block (pairs
// (j,31-j)+(j+8,23-j), 66 tile-computes each, grid 512) -> staging/barriers
// per unit work halved; (b) GEMM BK=64 single-buffer with XOR-swizzled LDS
// (both-sides, attn-proven pattern) -> half the barriers, no bank conflicts;
// GEMM double-buffer reverted (measured neutral, m99/m100 confirmed).

#define S_LEN 2048
#define NHEAD 16
#define DHEAD 64

typedef short bf16x8 __attribute__((ext_vector_type(8)));
typedef float f32x4  __attribute__((ext_vector_type(4)));

__device__ __forceinline__ float bf2f(unsigned short u) {
    unsigned x = ((unsigned)u) << 16;
    return __builtin_bit_cast(float, x);
}
__device__ __forceinline__ unsigned short f2bf(float f) {   // RNE
    unsigned u = __builtin_bit_cast(unsigned, f);
    unsigned r = u + 0x7fff + ((u >> 16) & 1);
    return (unsigned short)(r >> 16);
}
__device__ __forceinline__ unsigned pack2(float lo, float hi) {  // 2xf32 -> packed 2xbf16
    return (unsigned)f2bf(lo) | ((unsigned)f2bf(hi) << 16);
}
__device__ __forceinline__ void gl16(const void* g, void* l) {
    __builtin_amdgcn_global_load_lds(
        (const __attribute__((address_space(1))) unsigned int*)g,
        (__attribute__((address_space(3))) unsigned int*)l, 16, 0, 0);
}

// ---------------------------------------------------------------------------
// f32 -> bf16 cast, 8 elems/thread (for x)
// ---------------------------------------------------------------------------
__global__ void cast_f32_bf16(const float* __restrict__ in,
                              unsigned* __restrict__ out, int n)
{
    const int i = (blockIdx.x * 256 + threadIdx.x) * 8;
    if (i >= n) return;
    const float4 a = *(const float4*)(in + i);
    const float4 b = *(const float4*)(in + i + 4);
    uint4 o;
    o.x = pack2(a.x, a.y); o.y = pack2(a.z, a.w);
    o.z = pack2(b.x, b.y); o.w = pack2(b.z, b.w);
    *(uint4*)(out + i / 2) = o;
}

// Fused cast of wq/wk/wv/wo (1M elems each) in one launch.
__global__ void cast_w4(const float* __restrict__ wq, const float* __restrict__ wk,
                        const float* __restrict__ wv, const float* __restrict__ wo,
                        unsigned* __restrict__ Wb, unsigned* __restrict__ Wob)
{
    const int idx = blockIdx.x * 256 + threadIdx.x;     // 524288 total threads
    const int sel = idx >> 17;                          // 0..3 (131072 thr each)
    const int loc = idx & 131071;
    const float* src = (sel == 0) ? wq : (sel == 1) ? wk : (sel == 2) ? wv : wo;
    unsigned* dst = (sel == 3) ? Wob : Wb + (size_t)sel * 524288;
    const int i = loc * 8;
    const float4 a = *(const float4*)(src + i);
    const float4 b = *(const float4*)(src + i + 4);
    uint4 o;
    o.x = pack2(a.x, a.y); o.y = pack2(a.z, a.w);
    o.z = pack2(b.x, b.y); o.w = pack2(b.z, b.w);
    *(uint4*)(dst + i / 2) = o;
}

// ---------------------------------------------------------------------------
// NT GEMM, bf16 MFMA, BK=64 + XOR-swizzled LDS: C = A[M,1024] * B[N,1024]^T
// 128x128 tile, 256 thr (4 waves 2x2), 4x4 frags, 2 barriers per 64-K chunk
// (16 chunks -> 32 barriers). LDS rows are 128B: linear dest + inverse-swz
// source + swz read (rule 21; (row&7) invariant across the 4 staging instrs
// and equals (ln&7) on the read side since offsets are multiples of 8).
// MODE 0: QKV — scatter bf16 to Qb/Kb [bh][s][64] and Vt [bh][dh][2048].
// MODE 1: OUT — f32 store to Co[M][1024].
// ---------------------------------------------------------------------------
template <int MODE>
__global__ __launch_bounds__(256, 2) void gemm_bt(
    const unsigned short* __restrict__ A,
    const unsigned short* __restrict__ Bw,
    unsigned short* __restrict__ Qb,
    unsigned short* __restrict__ Kb,
    unsigned short* __restrict__ Vt,
    float* __restrict__ Co)
{
    __shared__ __align__(16) unsigned short As[128 * 64];   // 16KB
    __shared__ __align__(16) unsigned short Bs[128 * 64];   // 16KB

    const int t    = threadIdx.x;
    const int bm   = blockIdx.x * 128;
    const int bn   = blockIdx.y * 128;
    const int lane = t & 63, wv = t >> 6;
    const int wr   = wv >> 1, wc = wv & 1;
    const int ln   = lane & 15, ko = lane >> 4;

    f32x4 acc[4][4];
    #pragma unroll
    for (int i = 0; i < 4; ++i)
        #pragma unroll
        for (int j = 0; j < 4; ++j)
            acc[i][j] = f32x4{0.f, 0.f, 0.f, 0.f};

    const int sr  = t >> 3;                    // 0..31 staging row
    const int sg  = t & 7;                     // 16B segment (8 per 128B row)
    const int swz = (sg ^ (sr & 7)) * 8;       // inverse-swizzled source seg
    const unsigned short* aptr = A  + (size_t)(bm + sr) * 1024 + swz;
    const unsigned short* bptr = Bw + (size_t)(bn + sr) * 1024 + swz;

    for (int k0 = 0; k0 < 1024; k0 += 64) {
        __syncthreads();
        #pragma unroll
        for (int i = 0; i < 4; ++i) {          // rows sr + i*32
            gl16(aptr + k0 + i * 32 * 1024, (char*)As + t * 16 + i * 4096);
            gl16(bptr + k0 + i * 32 * 1024, (char*)Bs + t * 16 + i * 4096);
        }
        __syncthreads();

        #pragma unroll
        for (int s = 0; s < 2; ++s) {
            bf16x8 af[4], bfr[4];
            #pragma unroll
            for (int i = 0; i < 4; ++i)
                af[i] = *(const bf16x8*)((const char*)As +
                         (wr * 64 + i * 16 + ln) * 128 + (((s * 4 + ko) ^ (ln & 7)) * 16));
            #pragma unroll
            for (int j = 0; j < 4; ++j)
                bfr[j] = *(const bf16x8*)((const char*)Bs +
                         (wc * 64 + j * 16 + ln) * 128 + (((s * 4 + ko) ^ (ln & 7)) * 16));
            #pragma unroll
            for (int i = 0; i < 4; ++i)
                #pragma unroll
                for (int j = 0; j < 4; ++j)
                    acc[i][j] = __builtin_amdgcn_mfma_f32_16x16x32_bf16(
                        af[i], bfr[j], acc[i][j], 0, 0, 0);
        }
    }

    #pragma unroll
    for (int i = 0; i < 4; ++i) {
        const int mb = bm + wr * 64 + i * 16 + ko * 4;   // 4 consecutive rows mb..mb+3
        #pragma unroll
        for (int j = 0; j < 4; ++j) {
            const int n = bn + wc * 64 + j * 16 + ln;
            if constexpr (MODE == 0) {
                const int which = n >> 10, nh = n & 1023;
                const int h = nh >> 6, dh = nh & 63;
                const int bb = mb >> 11, s = mb & 2047;
                const int bh = bb * NHEAD + h;
                if (which == 2) {
                    uint2 pk;
                    pk.x = pack2(acc[i][j][0], acc[i][j][1]);
                    pk.y = pack2(acc[i][j][2], acc[i][j][3]);
                    *(uint2*)&Vt[((size_t)bh * 64 + dh) * 2048 + s] = pk;
                } else {
                    unsigned short* dst = which ? Kb : Qb;
                    #pragma unroll
                    for (int r = 0; r < 4; ++r)
                        dst[((size_t)bh * 2048 + (s + r)) * 64 + dh] = f2bf(acc[i][j][r]);
                }
            } else {
                #pragma unroll
                for (int r = 0; r < 4; ++r)
                    Co[(size_t)(mb + r) * 1024 + n] = acc[i][j][r];
            }
        }
    }
}

// ---------------------------------------------------------------------------
// RoPE in-place on bf16 Q,K ([bh][s][64], interleaved pairs)
// ---------------------------------------------------------------------------
__global__ void rope_kernel(unsigned int* __restrict__ Qb, unsigned int* __restrict__ Kb)
{
    const int idx  = blockIdx.x * 256 + threadIdx.x;  // 64*2048*32 pairs
    const int i    = idx & 31;
    const int srow = (idx >> 5) & 2047;

    const float inv = powf(10000.0f, -(float)i * (1.0f / 32.0f));
    const float ang = (float)srow * inv;
    float sn, cs;
    sincosf(ang, &sn, &cs);

    const unsigned q = Qb[idx];
    const unsigned k = Kb[idx];
    const float qx = bf2f((unsigned short)(q & 0xffff)), qy = bf2f((unsigned short)(q >> 16));
    const float kx = bf2f((unsigned short)(k & 0xffff)), ky = bf2f((unsigned short)(k >> 16));
    Qb[idx] = pack2(qx * cs - qy * sn, qx * sn + qy * cs);
    Kb[idx] = pack2(kx * cs - ky * sn, kx * sn + ky * cs);
}

// ---------------------------------------------------------------------------
// One 64-key tile for one 64-q tile, swapped orientation + defer-max (T13):
// sv[nf] = mfma(K,Q): lane (ln,koct) holds P[q=w*16+ln][key=nf*16+koct*4+r].
// When __all(mx <= m+8) keep old max (skip al + ao-rescale); P bounded e^8.
// ---------------------------------------------------------------------------
__device__ __forceinline__ void process_tile(
    const char* __restrict__ Ks, const char* __restrict__ Vs, char* pb,
    const bf16x8 qf[2], f32x4 ao[4], float& m_i, float& l_i,
    int ln, int koct, int qrow, bool diag)
{
    // ---- QK^T (swapped): sv[nf][r] = P[qrow][nf*16+koct*4+r] ----
    f32x4 sv[4];
    #pragma unroll
    for (int nf = 0; nf < 4; ++nf) sv[nf] = f32x4{0.f, 0.f, 0.f, 0.f};
    #pragma unroll
    for (int s = 0; s < 2; ++s) {
        #pragma unroll
        for (int nf = 0; nf < 4; ++nf) {
            const int key = nf * 16 + ln;
            const bf16x8 kf = *(const bf16x8*)(Ks + key * 128 + (((s * 4 + koct) ^ (key & 7)) * 16));
            sv[nf] = __builtin_amdgcn_mfma_f32_16x16x32_bf16(kf, qf[s], sv[nf], 0, 0, 0);
        }
    }

    if (diag) {   // causal mask: key > qrow
        #pragma unroll
        for (int nf = 0; nf < 4; ++nf) {
            #pragma unroll
            for (int r = 0; r < 4; ++r)
                if (nf * 16 + koct * 4 + r > qrow) sv[nf][r] = -INFINITY;
        }
    }

    // ---- online softmax, one row per lane; defer-max THR=8 ----
    float mx = sv[0][0];
    #pragma unroll
    for (int nf = 0; nf < 4; ++nf)
        #pragma unroll
        for (int r = 0; r < 4; ++r) mx = fmaxf(mx, sv[nf][r]);
    mx = fmaxf(mx, __shfl_xor(mx, 16));
    mx = fmaxf(mx, __shfl_xor(mx, 32));

    if (!__all(mx <= m_i + 8.0f)) {      // growth too large -> rescale
        const float mn = fmaxf(m_i, mx);
        const float al = __expf(m_i - mn);
        m_i = mn;
        l_i *= al;
        float alr[4];
        #pragma unroll
        for (int r = 0; r < 4; ++r) alr[r] = __shfl(al, koct * 4 + r);
        #pragma unroll
        for (int nf = 0; nf < 4; ++nf)
            #pragma unroll
            for (int r = 0; r < 4; ++r)
                ao[nf][r] *= alr[r];
    }

    float sum = 0.f;
    #pragma unroll
    for (int nf = 0; nf < 4; ++nf)
        #pragma unroll
        for (int r = 0; r < 4; ++r) {
            const float pv = __expf(sv[nf][r] - m_i);
            sv[nf][r] = pv;
            sum += pv;
        }
    sum += __shfl_xor(sum, 16);
    sum += __shfl_xor(sum, 32);
    l_i += sum;

    // ---- P -> per-wave LDS: 4x b64, key-contiguous packs ----
    #pragma unroll
    for (int nf = 0; nf < 4; ++nf) {
        uint2 pk;
        pk.x = pack2(sv[nf][0], sv[nf][1]);
        pk.y = pack2(sv[nf][2], sv[nf][3]);
        *(uint2*)(pb + ln * 128 + ((nf * 32 + koct * 8) ^ ((ln & 7) << 4))) = pk;
    }
    // wave-private P; same-wave lgkm ordering handled by compiler

    // ---- PV: O[16q][64dh] += P[16,64] * V[64,64] ----
    #pragma unroll
    for (int s2 = 0; s2 < 2; ++s2) {
        const bf16x8 pa = *(const bf16x8*)(pb + ln * 128 + (((s2 * 4 + koct) ^ (ln & 7)) * 16));
        #pragma unroll
        for (int nf = 0; nf < 4; ++nf) {
            const int dh = nf * 16 + ln;
            const bf16x8 vf = *(const bf16x8*)(Vs + dh * 128 + (((s2 * 4 + koct) ^ (dh & 7)) * 16));
            ao[nf] = __builtin_amdgcn_mfma_f32_16x16x32_bf16(pa, vf, ao[nf], 0, 0, 0);
        }
    }
}

// ---------------------------------------------------------------------------
// MFMA flash attention, causal, FOUR q-tiles per block: (j,31-j,j+8,23-j)
// -> 66 tile-computes per block (balanced), grid 512 = 2 blocks/CU.
// K/V double-buffered, next tile staged before computing current; one
// K/V stage now serves up to 4 tile-computes. XCD-grouped: all 8 blocks of a
// bh share bid&7 (same XCD L2); 8 bh per XCD = 4MB K/V.
// ---------------------------------------------------------------------------
__global__ __launch_bounds__(256, 2) void attn_mfma(
    const unsigned short* __restrict__ Qb,
    const unsigned short* __restrict__ Kb,
    const unsigned short* __restrict__ Vt,
    unsigned short* __restrict__ Aot)
{
    __shared__ __align__(16) unsigned short Ksh[2][64 * 64];
    __shared__ __align__(16) unsigned short Vsh[2][64 * 64];
    __shared__ __align__(16) unsigned short Psh[4 * 16 * 64];

    const int t    = threadIdx.x;
    const int lane = t & 63, w = t >> 6;
    const int ln   = lane & 15, koct = lane >> 4;
    const int bid  = blockIdx.x;               // 0..511
    const int xcd  = bid & 7;
    const int i2   = bid >> 3;                 // 0..63
    const int bh   = xcd + 8 * (i2 & 7);
    const int j    = i2 >> 3;                  // 0..7
    const int qts[4] = {31 - j, 23 - j, j + 8, j};   // decreasing kt-extent
    const size_t kvbase = (size_t)bh * S_LEN * DHEAD;
    const size_t vtbase = (size_t)bh * DHEAD * S_LEN;

    // Q fragments for all four tiles, pre-scaled by 1/8 (exact in bf16)
    bf16x8 qf[4][2];
    #pragma unroll
    for (int u = 0; u < 4; ++u) {
        #pragma unroll
        for (int s = 0; s < 2; ++s) {
            bf16x8 v = *(const bf16x8*)(Qb + kvbase +
                (size_t)(qts[u] * 64 + w * 16 + ln) * 64 + s * 32 + koct * 8);
            #pragma unroll
            for (int e = 0; e < 8; ++e)
                v[e] = (short)f2bf(bf2f((unsigned short)v[e]) * 0.125f);
            qf[u][s] = v;
        }
    }

    f32x4 ao[4][4];
    float m_i[4], l_i[4];
    #pragma unroll
    for (int u = 0; u < 4; ++u) {
        m_i[u] = -INFINITY; l_i[u] = 0.f;
        #pragma unroll
        for (int nf = 0; nf < 4; ++nf) ao[u][nf] = f32x4{0.f, 0.f, 0.f, 0.f};
    }

    const int kr = t >> 3;        // staging row, +32 for second instr
    const int sg = t & 7;         // 16B segment within 128B row
    const int kr2 = kr + 32;
    const int qrow = w * 16 + ln; // this lane's softmax row (within 64-tile)
    const int ktmax = qts[0];

    // prologue: stage kt=0 into buffer 0
    gl16(Kb + kvbase + (size_t)kr  * 64 + (sg ^ (kr  & 7)) * 8, (char*)&Ksh[0][0] + t * 16);
    gl16(Kb + kvbase + (size_t)kr2 * 64 + (sg ^ (kr2 & 7)) * 8, (char*)&Ksh[0][0] + (t + 256) * 16);
    gl16(Vt + vtbase + (size_t)kr  * S_LEN + (sg ^ (kr  & 7)) * 8, (char*)&Vsh[0][0] + t * 16);
    gl16(Vt + vtbase + (size_t)kr2 * S_LEN + (sg ^ (kr2 & 7)) * 8, (char*)&Vsh[0][0] + (t + 256) * 16);
    __syncthreads();   // drain -> buf0 visible

    char* pb = (char*)Psh + w * 2048;
    int cur = 0;

    for (int kt = 0; kt <= ktmax; ++kt) {
        if (kt < ktmax) {   // issue next tile's staging early (hides HBM latency)
            const int c1 = (kt + 1) * 64;
            gl16(Kb + kvbase + (size_t)(c1 + kr)  * 64 + (sg ^ (kr  & 7)) * 8, (char*)&Ksh[cur ^ 1][0] + t * 16);
            gl16(Kb + kvbase + (size_t)(c1 + kr2) * 64 + (sg ^ (kr2 & 7)) * 8, (char*)&Ksh[cur ^ 1][0] + (t + 256) * 16);
            gl16(Vt + vtbase + (size_t)kr  * S_LEN + c1 + (sg ^ (kr  & 7)) * 8, (char*)&Vsh[cur ^ 1][0] + t * 16);
            gl16(Vt + vtbase + (size_t)kr2 * S_LEN + c1 + (sg ^ (kr2 & 7)) * 8, (char*)&Vsh[cur ^ 1][0] + (t + 256) * 16);
        }

        const char* Ks = (const char*)&Ksh[cur][0];
        const char* Vs = (const char*)&Vsh[cur][0];

        process_tile(Ks, Vs, pb, qf[0], ao[0], m_i[0], l_i[0], ln, koct, qrow, kt == qts[0]);
        if (kt <= qts[1])
            process_tile(Ks, Vs, pb, qf[1], ao[1], m_i[1], l_i[1], ln, koct, qrow, kt == qts[1]);
        if (kt <= qts[2])
            process_tile(Ks, Vs, pb, qf[2], ao[2], m_i[2], l_i[2], ln, koct, qrow, kt == qts[2]);
        if (kt <= qts[3])
            process_tile(Ks, Vs, pb, qf[3], ao[3], m_i[3], l_i[3], ln, koct, qrow, kt == qts[3]);

        __syncthreads();   // implicit vmcnt/lgkm drain: next buffer published
        cur ^= 1;
    }

    // ---- epilogue: Aot [b][s][h*64+dh] bf16, all four tiles ----
    const int b = bh >> 4, h = bh & 15;
    #pragma unroll
    for (int u = 0; u < 4; ++u) {
        float lr[4];
        #pragma unroll
        for (int r = 0; r < 4; ++r) lr[r] = __shfl(l_i[u], koct * 4 + r);
        #pragma unroll
        for (int r = 0; r < 4; ++r) {
            const float inv = 1.0f / lr[r];
            const int s = qts[u] * 64 + w * 16 + koct * 4 + r;
            #pragma unroll
            for (int nf = 0; nf < 4; ++nf)
                Aot[(size_t)(b * S_LEN + s) * 1024 + h * 64 + nf * 16 + ln] =
                    f2bf(ao[u][nf][r] * inv);
        }
    }
}

// ---------------------------------------------------------------------------
extern "C" void kernel_launch(void* const* d_in, const int* in_sizes, int n_in,
                              void* d_out, int out_size, void* d_ws, size_t ws_size,
                              hipStream_t stream)
{
    const float* x  = (const float*)d_in[0];
    const float* wq = (const float*)d_in[1];
    const float* wk = (const float*)d_in[2];
    const float* wv = (const float*)d_in[3];
    const float* wo = (const float*)d_in[4];
    float* out = (float*)d_out;

    char* p = (char*)d_ws;
    unsigned short* Xb  = (unsigned short*)p;                          // 16 MB
    unsigned short* Wb  = (unsigned short*)(p + ((size_t)16 << 20));   // 6 MB [3072][1024]
    unsigned short* Wob = (unsigned short*)(p + ((size_t)22 << 20));   // 2 MB
    unsigned short* Qb  = (unsigned short*)(p + ((size_t)24 << 20));   // 16 MB [bh][s][64]
    unsigned short* Kb  = (unsigned short*)(p + ((size_t)40 << 20));   // 16 MB
    unsigned short* Vt  = (unsigned short*)(p + ((size_t)56 << 20));   // 16 MB [bh][dh][s]
    unsigned short* Aot = (unsigned short*)(p + ((size_t)72 << 20));   // 16 MB [b][s][1024]

    const int NX = 8192 * 1024;
    cast_f32_bf16<<<NX / 2048, 256, 0, stream>>>(x, (unsigned*)Xb, NX);
    cast_w4<<<2048, 256, 0, stream>>>(wq, wk, wv, wo, (unsigned*)Wb, (unsigned*)Wob);

    gemm_bt<0><<<dim3(64, 24), 256, 0, stream>>>(Xb, Wb, Qb, Kb, Vt, nullptr);
    rope_kernel<<<16384, 256, 0, stream>>>((unsigned int*)Qb, (unsigned int*)Kb);
    attn_mfma<<<512, 256, 0, stream>>>(Qb, Kb, Vt, Aot);
    gemm_bt<1><<<dim3(64, 8), 256, 0, stream>>>(Aot, Wob, nullptr, nullptr, nullptr, out);
}